// Round 1
// 230.508 us; speedup vs baseline: 1.0019x; 1.0019x over previous
//
#include <hip/hip_runtime.h>
#include <math.h>

// ---------------------------------------------------------------------------
// bf16-MFMA pipeline v5:
//   wcast       : w_qkv fp32 -> Wfm frag-major bf16 (once; enables gl2lds B)
//   gemm_qkv    : BM=64 (grid 768 = 3 blocks/CU), B via double-buffered
//                 gl2lds + counted vmcnt, A via reg-prefetch + native cvt +
//                 XOR-swizzled ds_write, raw s_barrier pipeline
//   transpose_v : V plain -> Vfm (unchanged)
//   flash_attn3 : K/V double-buffered gl2lds pipeline (vmcnt(8), never 0 in
//                 loop), setprio around MFMA, base-2 softmax
//   fa_combine  : merge splits (exp2 to match base-2 m/l)
//   gemm_out    : unchanged
// Layout: addr(tile,c,r,j) = ((tile*NC + c)*64 + r)*8 + j  (NC = K/8)
// ---------------------------------------------------------------------------

typedef __attribute__((ext_vector_type(8))) short bf16x8;
typedef __attribute__((ext_vector_type(4))) float f32x4;

#define FA_SCL2 0.12751886525137387f   // 128^-0.5 * log2(e)

__device__ __forceinline__ unsigned short f2bf(float f) {
    __bf16 h = (__bf16)f;                       // native cvt (RNE), m240
    return __builtin_bit_cast(unsigned short, h);
}
__device__ __forceinline__ float bf2f(unsigned short h) {
    union { unsigned u; float f; } v; v.u = ((unsigned)h) << 16;
    return v.f;
}
__device__ __forceinline__ f32x4 mfma16(bf16x8 a, bf16x8 b, f32x4 c) {
    return __builtin_amdgcn_mfma_f32_16x16x32_bf16(a, b, c, 0, 0, 0);
}
__device__ __forceinline__ void gl2lds16(const void* g, void* l) {
    __builtin_amdgcn_global_load_lds(
        (const __attribute__((address_space(1))) unsigned int*)g,
        (__attribute__((address_space(3))) unsigned int*)l, 16, 0, 0);
}
__device__ __forceinline__ f32x4 vmax4(f32x4 a, f32x4 b) {
    return f32x4{fmaxf(a[0], b[0]), fmaxf(a[1], b[1]),
                 fmaxf(a[2], b[2]), fmaxf(a[3], b[3])};
}

// ---------------------------------------------------------------------------
// W fp32 [384][1024] -> frag-major bf16: granule(kc, r) at (kc*384 + r)*8.
// grid 192 x 256 thr. Coalesced reads, scattered 16B writes (0.75 MB total).
// ---------------------------------------------------------------------------
__global__ __launch_bounds__(256)
void wcast(const float* __restrict__ W, unsigned short* __restrict__ wfm)
{
    const int idx = blockIdx.x * 256 + threadIdx.x;   // 49152 granules
    const int kc = idx & 127, r = idx >> 7;
    const float* g = W + (size_t)r * 1024 + kc * 8;
    float4 w0 = *(const float4*)g, w1 = *(const float4*)(g + 4);
    bf16x8 p;
    p[0] = (short)f2bf(w0.x); p[1] = (short)f2bf(w0.y);
    p[2] = (short)f2bf(w0.z); p[3] = (short)f2bf(w0.w);
    p[4] = (short)f2bf(w1.x); p[5] = (short)f2bf(w1.y);
    p[6] = (short)f2bf(w1.z); p[7] = (short)f2bf(w1.w);
    *(bf16x8*)&wfm[(size_t)(kc * 384 + r) * 8] = p;
}

// ---------------------------------------------------------------------------
// QKV projection. BM=64, BN=128, BK=32. grid(256,3) x 256 thr.
// nb=0 -> Qfm, nb=128 -> Kfm (frag-major), nb=256 -> V plain [m][128].
// Pipeline: raw s_barrier, B dbuf via gl2lds (vmcnt counted), A reg-prefetch.
// ---------------------------------------------------------------------------
__global__ __launch_bounds__(256)
void gemm_qkv(const float* __restrict__ X, const unsigned short* __restrict__ Wfm,
              unsigned short* __restrict__ qfm, unsigned short* __restrict__ kfm,
              unsigned short* __restrict__ vpl)
{
    __shared__ unsigned short Asl[4 * 64 * 8];        // 4 KB, XOR row swizzle
    __shared__ unsigned short Bsl[2][4 * 128 * 8];    // 2 x 8 KB, linear (DMA)
    const int tid = threadIdx.x;
    const int mb = blockIdx.x * 64;
    const int nb = blockIdx.y * 128;
    const int wv = tid >> 6, lane = tid & 63;
    const int wr = (wv >> 1) * 32, wc = (wv & 1) * 64;
    const int lm = lane & 15, quad = lane >> 4;
    const int ar = tid >> 2, ac = tid & 3;

    f32x4 acc[2][4];
    #pragma unroll
    for (int i = 0; i < 2; ++i)
        #pragma unroll
        for (int j = 0; j < 4; ++j) acc[i][j] = f32x4{0.f, 0.f, 0.f, 0.f};

    // A prefetch (fp32, 32B/thread); consumed next iteration
    const float* gx = X + (size_t)(mb + ar) * 1024 + ac * 8;
    float4 a0 = *(const float4*)gx;
    float4 a1 = *(const float4*)(gx + 4);

    // B staging: wave wv stages k-chunk sc=wv, row halves h=0,1 (1 KB each)
    const unsigned short* wbase = Wfm + ((size_t)nb + lane) * 8;
    auto issueB = [&](int ktp, int buf) {
        const unsigned short* gsrc = wbase + (size_t)(((ktp >> 3) + wv) * 384) * 8;
        gl2lds16(gsrc,          &Bsl[buf][(wv * 128) * 8]);
        gl2lds16(gsrc + 64 * 8, &Bsl[buf][(wv * 128 + 64) * 8]);
    };
    issueB(0, 0);

    int bufc = 0;
    for (int kt = 0; kt < 1024; kt += 32) {
        __builtin_amdgcn_s_barrier();                 // B1: LDS free to overwrite
        const bool last = (kt == 992);
        if (!last) issueB(kt + 32, bufc ^ 1);
        {   // convert this tile's A regs -> LDS (XOR row swizzle: r ^ 2*sc)
            bf16x8 pk;
            pk[0] = (short)f2bf(a0.x); pk[1] = (short)f2bf(a0.y);
            pk[2] = (short)f2bf(a0.z); pk[3] = (short)f2bf(a0.w);
            pk[4] = (short)f2bf(a1.x); pk[5] = (short)f2bf(a1.y);
            pk[6] = (short)f2bf(a1.z); pk[7] = (short)f2bf(a1.w);
            *(bf16x8*)&Asl[(ac * 64 + (ar ^ (ac << 1))) * 8] = pk;
        }
        if (!last) {
            const float* g2 = gx + kt + 32;           // next-tile A, in flight
            a0 = *(const float4*)g2;                  // across compute phase
            a1 = *(const float4*)(g2 + 4);
            asm volatile("s_waitcnt vmcnt(4) lgkmcnt(0)" ::: "memory");
        } else {
            asm volatile("s_waitcnt vmcnt(0) lgkmcnt(0)" ::: "memory");
        }
        __builtin_amdgcn_s_barrier();                 // B2: tile ready
        bf16x8 af[2], bfr[4];
        #pragma unroll
        for (int i = 0; i < 2; ++i)
            af[i] = *(const bf16x8*)&Asl[(quad * 64 +
                        ((wr + i * 16 + lm) ^ (quad << 1))) * 8];
        #pragma unroll
        for (int j = 0; j < 4; ++j)
            bfr[j] = *(const bf16x8*)&Bsl[bufc][(quad * 128 + wc + j * 16 + lm) * 8];
        #pragma unroll
        for (int i = 0; i < 2; ++i)
            #pragma unroll
            for (int j = 0; j < 4; ++j)
                acc[i][j] = mfma16(af[i], bfr[j], acc[i][j]);
        bufc ^= 1;
    }

    if (nb == 256) {                      // V: plain row-major
        #pragma unroll
        for (int i = 0; i < 2; ++i)
            #pragma unroll
            for (int j = 0; j < 4; ++j)
                #pragma unroll
                for (int r = 0; r < 4; ++r)
                    vpl[(size_t)(mb + wr + i * 16 + quad * 4 + r) * 128
                        + wc + j * 16 + lm] = f2bf(acc[i][j][r]);
    } else {                              // Q/K: frag-major 64-row tiles
        unsigned short* dst = (nb == 0) ? qfm : kfm;
        const int tile = blockIdx.x;      // mb >> 6
        #pragma unroll
        for (int i = 0; i < 2; ++i)
            #pragma unroll
            for (int j = 0; j < 4; ++j) {
                const size_t cb = (size_t)(tile * 16 + (wc >> 3) + j * 2 + (lm >> 3)) * 512
                                  + (lm & 7);
                #pragma unroll
                for (int r = 0; r < 4; ++r)
                    dst[cb + (size_t)(wr + i * 16 + quad * 4 + r) * 8] = f2bf(acc[i][j][r]);
            }
    }
}

// ---------------------------------------------------------------------------
// V plain -> Vfm: per (b, 64-key tile): addr = ((b*64+kt)*8 + c)*1024 + d*8 + j
// where key = kt*64 + c*8 + j, d in [0,128). grid 256 x 256 thr.
// ---------------------------------------------------------------------------
__global__ __launch_bounds__(256)
void transpose_v(const unsigned short* __restrict__ V, unsigned short* __restrict__ Vfm)
{
    __shared__ unsigned short T[128 * 72];   // [d][key-rel], stride 72
    const int tid = threadIdx.x;
    const int b  = blockIdx.x >> 6;
    const int kt = blockIdx.x & 63;
    const unsigned short* src = V + ((size_t)b * 4096 + kt * 64) * 128;
    #pragma unroll
    for (int i = 0; i < 4; ++i) {
        const int idx = tid + i * 256;
        const int key = idx >> 4, c8 = (idx & 15) * 8;
        bf16x8 d = *(const bf16x8*)(src + key * 128 + c8);
        #pragma unroll
        for (int e = 0; e < 8; ++e) T[(c8 + e) * 72 + key] = (unsigned short)d[e];
    }
    __syncthreads();
    unsigned short* dst = Vfm + (size_t)(b * 64 + kt) * 8192;
    #pragma unroll
    for (int i = 0; i < 4; ++i) {
        const int o = tid + i * 256;          // d = o&127, c = o>>7
        const int d = o & 127, c = o >> 7;
        bf16x8 x = *(const bf16x8*)&T[d * 72 + c * 8];
        *(bf16x8*)(dst + ((size_t)c * 128 + d) * 8) = x;   // coalesced store
    }
}

// ---------------------------------------------------------------------------
// Flash attention v5: 256 thr (4 waves), Br=64 (wave owns 16 rows), Bc=64.
// K/V double-buffered gl2lds pipeline (vmcnt(8) in steady state), raw
// barriers, setprio around MFMA, base-2 online softmax. KV-split x4.
// LDS 72 KB -> 2 blocks/CU.
// ---------------------------------------------------------------------------
__global__ __launch_bounds__(256, 2)
void flash_attn3(const unsigned short* __restrict__ Qfm, const unsigned short* __restrict__ Kfm,
                 const unsigned short* __restrict__ Vfm,
                 unsigned short* __restrict__ Opart, float* __restrict__ Ml)
{
    __shared__ unsigned short Klds[2][8192];    // 2 x 16 KB (Q stages in [0])
    __shared__ unsigned short Vlds[2][8192];    // 2 x 16 KB
    __shared__ unsigned short Plds[4][1024];    // per-wave P (A-frag), 8 KB

    const int tid = threadIdx.x;
    const int wv = tid >> 6, lane = tid & 63;
    const int lm = lane & 15, quad = lane >> 4;

    const int bx = blockIdx.x;
    const int b  = bx & 3;
    const int sp = (bx >> 2) & 3;
    const int qi = bx >> 4;                                  // 0..63
    const int qt = (qi & 1) ? (qi >> 1) : (63 - (qi >> 1));  // heavy/light pair
    const int n  = qt + 1;                                   // key tiles
    const int cnt = (n >> 2) + ((sp < (n & 3)) ? 1 : 0);
    const int ktb = sp * (n >> 2) + ((sp < (n & 3)) ? sp : (n & 3));
    const int kte = ktb + cnt;

    const size_t obase = (size_t)((b * 64 + qt) * 4 + sp) * 8192;
    const int    mlb   = ((b * 64 + qt) * 4 + sp) * 128;

    if (cnt == 0) {                      // neutral partial
        bf16x8 z = {0, 0, 0, 0, 0, 0, 0, 0};
        #pragma unroll
        for (int t = 0; t < 4; ++t)
            *(bf16x8*)&Opart[obase + (size_t)(tid + t * 256) * 8] = z;
        if (tid < 64) Ml[mlb + tid] = -INFINITY;
        else if (tid < 128) Ml[mlb + tid] = 0.f;
        return;
    }

    // stage Q tile into Klds[0], pull frags to regs
    {
        const size_t qb = (size_t)(b * 64 + qt) * 8192;
        #pragma unroll
        for (int i = 0; i < 4; ++i) {
            const int pc = wv * 4 + i;
            gl2lds16(Qfm + qb + pc * 512 + lane * 8, &Klds[0][pc * 512]);
        }
    }
    __syncthreads();                     // full drain: Q in LDS
    bf16x8 qf[4];
    #pragma unroll
    for (int c = 0; c < 4; ++c)
        qf[c] = *(const bf16x8*)&Klds[0][((c * 4 + quad) * 64 + wv * 16 + lm) * 8];
    asm volatile("s_waitcnt lgkmcnt(0)" ::: "memory");   // qf secured in regs
    __builtin_amdgcn_s_barrier();                        // all waves have Q

    // prologue: issue first K/V tile into buf 0 (overwrites Q region: safe)
    {
        const size_t kb = (size_t)(b * 64 + ktb) * 8192;
        #pragma unroll
        for (int i = 0; i < 4; ++i) {
            const int pc = wv * 4 + i;
            gl2lds16(Kfm + kb + pc * 512 + lane * 8, &Klds[0][pc * 512]);
            gl2lds16(Vfm + kb + pc * 512 + lane * 8, &Vlds[0][pc * 512]);
        }
    }

    f32x4 oacc[8];
    #pragma unroll
    for (int oc = 0; oc < 8; ++oc) oacc[oc] = f32x4{0.f, 0.f, 0.f, 0.f};
    f32x4 m4 = f32x4{-INFINITY, -INFINITY, -INFINITY, -INFINITY};
    f32x4 l4 = f32x4{0.f, 0.f, 0.f, 0.f};
    unsigned short* Pw = Plds[wv];

    int cur = 0;
    for (int kt = ktb; kt < kte; ++kt) {
        __builtin_amdgcn_s_barrier();    // B1: buf[cur^1] free to overwrite
        if (kt + 1 < kte) {              // issue next tile; keep 8 in flight
            const size_t kb = (size_t)(b * 64 + kt + 1) * 8192;
            unsigned short* kd = &Klds[cur ^ 1][0];
            unsigned short* vd = &Vlds[cur ^ 1][0];
            #pragma unroll
            for (int i = 0; i < 4; ++i) {
                const int pc = wv * 4 + i;
                gl2lds16(Kfm + kb + pc * 512 + lane * 8, kd + pc * 512);
                gl2lds16(Vfm + kb + pc * 512 + lane * 8, vd + pc * 512);
            }
            asm volatile("s_waitcnt vmcnt(8)" ::: "memory");  // prior tile done
        } else {
            asm volatile("s_waitcnt vmcnt(0)" ::: "memory");
        }
        __builtin_amdgcn_s_barrier();    // B2: buf[cur] ready for all waves
        const unsigned short* Kc = &Klds[cur][0];
        const unsigned short* Vc = &Vlds[cur][0];

        // S = Q K^T : wave's 16 rows x 64 keys (pre-scaled to base-2)
        f32x4 sv[4];
        __builtin_amdgcn_s_setprio(1);
        #pragma unroll
        for (int ct = 0; ct < 4; ++ct) {
            f32x4 a = f32x4{0.f, 0.f, 0.f, 0.f};
            #pragma unroll
            for (int c = 0; c < 4; ++c) {
                bf16x8 kf = *(const bf16x8*)&Kc[((c * 4 + quad) * 64 + ct * 16 + lm) * 8];
                a = mfma16(qf[c], kf, a);
            }
            sv[ct] = a * FA_SCL2;
        }
        __builtin_amdgcn_s_setprio(0);
        if (kt == qt) {                  // diagonal tile: mask key > row
            #pragma unroll
            for (int ct = 0; ct < 4; ++ct) {
                const int dg = ct * 16 + lm - wv * 16 - quad * 4;
                #pragma unroll
                for (int rr = 0; rr < 4; ++rr)
                    if (dg > rr) sv[ct][rr] = -INFINITY;
            }
        }
        // online softmax in base 2 (rows = quad's 16 lanes; in-quad butterfly)
        f32x4 rmax = vmax4(vmax4(sv[0], sv[1]), vmax4(sv[2], sv[3]));
        #pragma unroll
        for (int d = 1; d < 16; d <<= 1) {
            f32x4 o;
            #pragma unroll
            for (int e = 0; e < 4; ++e) o[e] = __shfl_xor(rmax[e], d);
            rmax = vmax4(rmax, o);
        }
        const f32x4 mnew = vmax4(m4, rmax);
        f32x4 alpha, rs = f32x4{0.f, 0.f, 0.f, 0.f};
        #pragma unroll
        for (int e = 0; e < 4; ++e) alpha[e] = __builtin_amdgcn_exp2f(m4[e] - mnew[e]);
        #pragma unroll
        for (int ct = 0; ct < 4; ++ct)
            #pragma unroll
            for (int rr = 0; rr < 4; ++rr) {
                const float p = __builtin_amdgcn_exp2f(sv[ct][rr] - mnew[rr]);
                sv[ct][rr] = p; rs[rr] += p;
            }
        #pragma unroll
        for (int d = 1; d < 16; d <<= 1) {
            f32x4 o;
            #pragma unroll
            for (int e = 0; e < 4; ++e) o[e] = __shfl_xor(rs[e], d);
            rs += o;
        }
        l4 = l4 * alpha + rs;
        m4 = mnew;
        // P -> wave-private LDS (A-frag layout), no barrier needed
        #pragma unroll
        for (int ct = 0; ct < 4; ++ct) {
            const int cb = ((ct * 2 + (lm >> 3)) * 16 + quad * 4) * 8 + (lm & 7);
            #pragma unroll
            for (int rr = 0; rr < 4; ++rr)
                Pw[cb + rr * 8] = f2bf(sv[ct][rr]);
        }
        #pragma unroll
        for (int oc = 0; oc < 8; ++oc) oacc[oc] *= alpha;
        // O += P V
        __builtin_amdgcn_s_setprio(1);
        #pragma unroll
        for (int s = 0; s < 2; ++s) {
            bf16x8 pf = *(const bf16x8*)&Pw[((s * 4 + quad) * 16 + lm) * 8];
            #pragma unroll
            for (int oc = 0; oc < 8; ++oc) {
                bf16x8 vf = *(const bf16x8*)&Vc[((s * 4 + quad) * 128 + oc * 16 + lm) * 8];
                oacc[oc] = mfma16(pf, vf, oacc[oc]);
            }
        }
        __builtin_amdgcn_s_setprio(0);
        cur ^= 1;
    }

    // epilogue: Opart (frag-major granules) + Ml (m in log2 units)
    #pragma unroll
    for (int oc = 0; oc < 8; ++oc) {
        const size_t cb = obase + (size_t)((oc * 2 + (lm >> 3)) * 64
                          + wv * 16 + quad * 4) * 8 + (lm & 7);
        #pragma unroll
        for (int rr = 0; rr < 4; ++rr)
            Opart[cb + rr * 8] = f2bf(oacc[oc][rr]);
    }
    if (lm == 0)
        #pragma unroll
        for (int rr = 0; rr < 4; ++rr) {
            const int row = wv * 16 + quad * 4 + rr;
            Ml[mlb + row] = m4[rr];
            Ml[mlb + 64 + row] = l4[rr];
        }
}

// ---------------------------------------------------------------------------
// Merge 4 splits -> Ofm (frag-major). grid 256 (= b*64+qt) x 256 thr.
// m/l are in base-2 units -> exp2 weights.
// ---------------------------------------------------------------------------
__global__ __launch_bounds__(256)
void fa_combine(const unsigned short* __restrict__ Opart, const float* __restrict__ Ml,
                unsigned short* __restrict__ Ofm)
{
    const int bq = blockIdx.x;
    const int tid = threadIdx.x;
    const size_t pbase = (size_t)bq * 4 * 8192;
    const int mlb = bq * 4 * 128;
    #pragma unroll
    for (int t = 0; t < 4; ++t) {
        const int g = tid + t * 256;          // granule: c = g>>6, r = g&63
        const int r = g & 63;
        float m[4], l[4];
        #pragma unroll
        for (int s = 0; s < 4; ++s) {
            m[s] = Ml[mlb + s * 128 + r];
            l[s] = Ml[mlb + s * 128 + 64 + r];
        }
        const float M = fmaxf(fmaxf(m[0], m[1]), fmaxf(m[2], m[3]));
        float a[4], den = 0.f;
        #pragma unroll
        for (int s = 0; s < 4; ++s) {
            a[s] = __builtin_amdgcn_exp2f(m[s] - M);
            den += a[s] * l[s];
        }
        const float rsc = 1.f / den;
        float acc[8] = {};
        #pragma unroll
        for (int s = 0; s < 4; ++s) {
            bf16x8 x = *(const bf16x8*)&Opart[pbase + (size_t)s * 8192 + (size_t)g * 8];
            #pragma unroll
            for (int e = 0; e < 8; ++e) acc[e] += a[s] * bf2f((unsigned short)x[e]);
        }
        bf16x8 o;
        #pragma unroll
        for (int e = 0; e < 8; ++e) o[e] = f2bf(acc[e] * rsc);
        *(bf16x8*)&Ofm[(size_t)bq * 8192 + (size_t)g * 8] = o;   // coalesced
    }
}

// ---------------------------------------------------------------------------
// Output projection + bias. A from Ofm (coalesced staging). grid(128,8)x256.
// ---------------------------------------------------------------------------
__global__ __launch_bounds__(256)
void gemm_out(const unsigned short* __restrict__ Ain, const float* __restrict__ W,
              const float* __restrict__ bias, float* __restrict__ out)
{
    __shared__ unsigned short Bsl[16 * 128 * 8];   // W tile (K=128), 32 KB
    __shared__ unsigned short Asl[8 * 64 * 8];     // per-BK32 A (2 subtiles), 8 KB
    const int tid = threadIdx.x;
    const int mb = blockIdx.x * 128;
    const int nb = blockIdx.y * 128;
    const int wv = tid >> 6, lane = tid & 63;
    const int wr = (wv >> 1) * 64, wc = (wv & 1) * 64;
    const int lm = lane & 15, quad = lane >> 4;

    {   // stage W once (fp32 -> bf16)
        const int r = tid >> 1;
        #pragma unroll
        for (int i = 0; i < 8; ++i) {
            const int c = (tid & 1) * 8 + i;
            const float* g = W + (size_t)(nb + r) * 128 + c * 8;
            float4 w0 = *(const float4*)g, w1 = *(const float4*)(g + 4);
            bf16x8 pw;
            pw[0] = (short)f2bf(w0.x); pw[1] = (short)f2bf(w0.y);
            pw[2] = (short)f2bf(w0.z); pw[3] = (short)f2bf(w0.w);
            pw[4] = (short)f2bf(w1.x); pw[5] = (short)f2bf(w1.y);
            pw[6] = (short)f2bf(w1.z); pw[7] = (short)f2bf(w1.w);
            *(bf16x8*)&Bsl[(c * 128 + r) * 8] = pw;
        }
    }

    f32x4 acc[4][4];
    #pragma unroll
    for (int i = 0; i < 4; ++i)
        #pragma unroll
        for (int j = 0; j < 4; ++j) acc[i][j] = f32x4{0.f, 0.f, 0.f, 0.f};

    for (int kt = 0; kt < 4; ++kt) {
        __syncthreads();
        #pragma unroll
        for (int i = 0; i < 2; ++i) {
            const int id = wv * 2 + i;          // 0..7: subtile t, chunk kcl
            const int t = id >> 2, kcl = id & 3;
            gl2lds16(Ain + ((size_t)(mb >> 6) + t) * 8192 + (kt * 4 + kcl) * 512 + lane * 8,
                     &Asl[(t * 4 + kcl) * 512]);
        }
        __syncthreads();
        bf16x8 af[4], bfr[4];
        #pragma unroll
        for (int i = 0; i < 4; ++i)
            af[i] = *(const bf16x8*)&Asl[(((wv >> 1) * 4 + quad) * 64 + i * 16 + lm) * 8];
        #pragma unroll
        for (int j = 0; j < 4; ++j)
            bfr[j] = *(const bf16x8*)&Bsl[((kt * 4 + quad) * 128 + wc + j * 16 + lm) * 8];
        #pragma unroll
        for (int i = 0; i < 4; ++i)
            #pragma unroll
            for (int j = 0; j < 4; ++j)
                acc[i][j] = mfma16(af[i], bfr[j], acc[i][j]);
    }

    #pragma unroll
    for (int j = 0; j < 4; ++j) {
        const int col = nb + wc + j * 16 + lm;
        const float bv = bias[col];
        #pragma unroll
        for (int i = 0; i < 4; ++i)
            #pragma unroll
            for (int r = 0; r < 4; ++r) {
                const int m = mb + wr + i * 16 + quad * 4 + r;
                out[(size_t)m * 1024 + col] = acc[i][j][r] + bv;
            }
    }
}

// ---------------------------------------------------------------------------
extern "C" void kernel_launch(void* const* d_in, const int* in_sizes, int n_in,
                              void* d_out, int out_size, void* d_ws, size_t ws_size,
                              hipStream_t stream)
{
    (void)in_sizes; (void)n_in; (void)out_size; (void)ws_size;
    const float* x     = (const float*)d_in[0];
    const float* w_qkv = (const float*)d_in[1];
    const float* w_out = (const float*)d_in[2];
    const float* b_out = (const float*)d_in[3];
    float* out = (float*)d_out;
    unsigned short* ws = (unsigned short*)d_ws;

    const size_t NE = (size_t)16384 * 128;          // 2 097 152
    unsigned short* qfm = ws;                        // 4 MB (Ofm aliases after flash)
    unsigned short* kfm = ws + NE;                   // 4 MB
    unsigned short* vpl = ws + 2 * NE;               // 4 MB
    unsigned short* vfm = ws + 3 * NE;               // 4 MB
    unsigned short* op  = ws + 4 * NE;               // Opart 4*NE = 16.8 MB
    float*          ml  = (float*)(ws + 8 * NE);     // 131072 floats = 0.5 MB
    unsigned short* ofm = qfm;                       // alias: Qfm dead after flash
    unsigned short* wfm = op;                        // alias: Opart dead until flash

    hipLaunchKernelGGL(wcast,       dim3(192),    dim3(256), 0, stream, w_qkv, wfm);
    hipLaunchKernelGGL(gemm_qkv,    dim3(256, 3), dim3(256), 0, stream, x, wfm, qfm, kfm, vpl);
    hipLaunchKernelGGL(transpose_v, dim3(256),    dim3(256), 0, stream, vpl, vfm);
    hipLaunchKernelGGL(flash_attn3, dim3(1024),   dim3(256), 0, stream, qfm, kfm, vfm, op, ml);
    hipLaunchKernelGGL(fa_combine,  dim3(256),    dim3(256), 0, stream, op, ml, ofm);
    hipLaunchKernelGGL(gemm_out,    dim3(128, 8), dim3(256), 0, stream, ofm, w_out, b_out, out);
}

// Round 2
// 220.242 us; speedup vs baseline: 1.0486x; 1.0466x over previous
//
#include <hip/hip_runtime.h>
#include <math.h>

// ---------------------------------------------------------------------------
// bf16-MFMA pipeline v6 — traffic reduction (both big kernels were cache-BW
// bound, not latency-bound):
//   wcast       : w_qkv fp32 -> Wfm frag-major bf16 (once)
//   gemm_qkv    : FUSED BN=384 (Q|K|V in one pass) -> X read ONCE from HBM;
//                 grid 256 x 512thr, B triple-buffered gl2lds (L2-resident W),
//                 A reg-prefetch + native cvt; FA scale folded into Q
//   transpose_v : V plain -> Vfm (unchanged)
//   woutcast    : w_out fp32 -> Wofm frag-major bf16 (into dead vpl region)
//   flash_attn3 : Br=128 (8 waves) halves K/V traffic; batch->XCD-pair
//                 pinning makes K/V (2 MB/batch) L2-resident; dbuf gl2lds
//   fa_combine  : unchanged (Opart format preserved)
//   gemm_out    : B from Wofm via gl2lds, A double-buffered, raw barriers
// Layout: addr(tile,c,r,j) = ((tile*NC + c)*64 + r)*8 + j  (NC = K/8)
// ---------------------------------------------------------------------------

typedef __attribute__((ext_vector_type(8))) short bf16x8;
typedef __attribute__((ext_vector_type(4))) short bf16x4;
typedef __attribute__((ext_vector_type(4))) float f32x4;

#define FA_SCL2 0.12751886525137387f   // 128^-0.5 * log2(e)

__device__ __forceinline__ unsigned short f2bf(float f) {
    __bf16 h = (__bf16)f;                       // native cvt (RNE)
    return __builtin_bit_cast(unsigned short, h);
}
__device__ __forceinline__ float bf2f(unsigned short h) {
    union { unsigned u; float f; } v; v.u = ((unsigned)h) << 16;
    return v.f;
}
__device__ __forceinline__ f32x4 mfma16(bf16x8 a, bf16x8 b, f32x4 c) {
    return __builtin_amdgcn_mfma_f32_16x16x32_bf16(a, b, c, 0, 0, 0);
}
__device__ __forceinline__ void gl2lds16(const void* g, void* l) {
    __builtin_amdgcn_global_load_lds(
        (const __attribute__((address_space(1))) unsigned int*)g,
        (__attribute__((address_space(3))) unsigned int*)l, 16, 0, 0);
}
__device__ __forceinline__ f32x4 vmax4(f32x4 a, f32x4 b) {
    return f32x4{fmaxf(a[0], b[0]), fmaxf(a[1], b[1]),
                 fmaxf(a[2], b[2]), fmaxf(a[3], b[3])};
}

// ---------------------------------------------------------------------------
// W fp32 [384][1024] -> frag-major bf16: granule(kc, r) at (kc*384 + r)*8.
// grid 192 x 256 thr.
// ---------------------------------------------------------------------------
__global__ __launch_bounds__(256)
void wcast(const float* __restrict__ W, unsigned short* __restrict__ wfm)
{
    const int idx = blockIdx.x * 256 + threadIdx.x;   // 49152 granules
    const int kc = idx & 127, r = idx >> 7;
    const float* g = W + (size_t)r * 1024 + kc * 8;
    float4 w0 = *(const float4*)g, w1 = *(const float4*)(g + 4);
    bf16x8 p;
    p[0] = (short)f2bf(w0.x); p[1] = (short)f2bf(w0.y);
    p[2] = (short)f2bf(w0.z); p[3] = (short)f2bf(w0.w);
    p[4] = (short)f2bf(w1.x); p[5] = (short)f2bf(w1.y);
    p[6] = (short)f2bf(w1.z); p[7] = (short)f2bf(w1.w);
    *(bf16x8*)&wfm[(size_t)(kc * 384 + r) * 8] = p;
}

// ---------------------------------------------------------------------------
// w_out fp32 [1024][128] -> frag-major bf16 64-row tiles:
// granule at ((rg>>6)*16 + c)*512 + (rg&63)*8. grid 64 x 256 thr.
// ---------------------------------------------------------------------------
__global__ __launch_bounds__(256)
void woutcast(const float* __restrict__ W, unsigned short* __restrict__ wofm)
{
    const int idx = blockIdx.x * 256 + threadIdx.x;   // 16384 granules
    const int c = idx & 15, rg = idx >> 4;            // rg in [0,1024)
    const float* g = W + (size_t)rg * 128 + c * 8;
    float4 w0 = *(const float4*)g, w1 = *(const float4*)(g + 4);
    bf16x8 p;
    p[0] = (short)f2bf(w0.x); p[1] = (short)f2bf(w0.y);
    p[2] = (short)f2bf(w0.z); p[3] = (short)f2bf(w0.w);
    p[4] = (short)f2bf(w1.x); p[5] = (short)f2bf(w1.y);
    p[6] = (short)f2bf(w1.z); p[7] = (short)f2bf(w1.w);
    *(bf16x8*)&wofm[((size_t)((rg >> 6) * 16 + c) * 64 + (rg & 63)) * 8] = p;
}

// ---------------------------------------------------------------------------
// Fused QKV projection. BM=64, BN=384 (Q|K|V), BK=32. grid 256 x 512 thr.
// X read exactly once. B triple-buffered via gl2lds from Wfm (L2-resident).
// Q written pre-scaled by FA_SCL2.
// ---------------------------------------------------------------------------
__global__ __launch_bounds__(512)
void gemm_qkv(const float* __restrict__ X, const unsigned short* __restrict__ Wfm,
              unsigned short* __restrict__ qfm, unsigned short* __restrict__ kfm,
              unsigned short* __restrict__ vpl)
{
    __shared__ unsigned short Asl[2048];          // 4 KB frag-major A (64x32)
    __shared__ unsigned short Bsl[3][12288];      // 3 x 24 KB (384x32)
    const int tid = threadIdx.x;
    const int wv = tid >> 6, lane = tid & 63;
    const int lm = lane & 15, quad = lane >> 4;
    const int mb = blockIdx.x * 64;
    const int arow = tid >> 3, af4 = tid & 7;     // A staging: row, float4 idx

    f32x4 acc[4][3];
    #pragma unroll
    for (int i = 0; i < 4; ++i)
        #pragma unroll
        for (int j = 0; j < 3; ++j) acc[i][j] = f32x4{0.f, 0.f, 0.f, 0.f};

    // A(0) prefetch (one float4/thread)
    const float* gx = X + (size_t)(mb + arow) * 1024 + af4 * 4;
    float4 a0 = *(const float4*)gx;

    // B staging: 24 pieces of 1 KB; wave wv stages pieces wv*3 + {0,1,2}
    auto issueB = [&](int it, int buf) {
        #pragma unroll
        for (int i = 0; i < 3; ++i) {
            const int p = wv * 3 + i;
            const int kcl = p & 3, rg = p >> 2;
            gl2lds16(Wfm + (size_t)((it * 4 + kcl) * 384 + rg * 64) * 8 + lane * 8,
                     &Bsl[buf][(kcl * 384 + rg * 64) * 8]);
        }
    };
    issueB(0, 0);
    issueB(1, 1);

    for (int i = 0; i < 32; ++i) {
        __builtin_amdgcn_s_barrier();             // B1: Asl/Bsl[(i+2)%3] free
        {   // A(i) regs -> LDS (frag-major granule halves)
            bf16x4 pk;
            pk[0] = (short)f2bf(a0.x); pk[1] = (short)f2bf(a0.y);
            pk[2] = (short)f2bf(a0.z); pk[3] = (short)f2bf(a0.w);
            *(bf16x4*)&Asl[((af4 >> 1) * 64 + arow) * 8 + (af4 & 1) * 4] = pk;
        }
        if (i < 31) a0 = *(const float4*)(gx + (i + 1) * 32);
        if (i < 30) issueB(i + 2, (i + 2) % 3);
        if (i < 30)       asm volatile("s_waitcnt vmcnt(7) lgkmcnt(0)" ::: "memory");
        else if (i == 30) asm volatile("s_waitcnt vmcnt(4) lgkmcnt(0)" ::: "memory");
        else              asm volatile("s_waitcnt vmcnt(0) lgkmcnt(0)" ::: "memory");
        __builtin_amdgcn_s_barrier();             // B2: tile i ready
        const unsigned short* Bc = Bsl[i % 3];
        bf16x8 afr[4], bfr[3];
        #pragma unroll
        for (int i4 = 0; i4 < 4; ++i4)
            afr[i4] = *(const bf16x8*)&Asl[(quad * 64 + i4 * 16 + lm) * 8];
        #pragma unroll
        for (int j = 0; j < 3; ++j)
            bfr[j] = *(const bf16x8*)&Bc[(quad * 384 + wv * 48 + j * 16 + lm) * 8];
        #pragma unroll
        for (int i4 = 0; i4 < 4; ++i4)
            #pragma unroll
            for (int j = 0; j < 3; ++j)
                acc[i4][j] = mfma16(afr[i4], bfr[j], acc[i4][j]);
    }

    // epilogue: cols 0-127 -> Q (scaled), 128-255 -> K, 256-383 -> V plain
    #pragma unroll
    for (int j = 0; j < 3; ++j) {
        const int ncg = wv * 48 + j * 16 + lm;    // frag never straddles 128
        const int sect = ncg >> 7, ncol = ncg & 127;
        if (sect == 2) {
            #pragma unroll
            for (int i = 0; i < 4; ++i)
                #pragma unroll
                for (int r = 0; r < 4; ++r)
                    vpl[(size_t)(mb + i * 16 + quad * 4 + r) * 128 + ncol]
                        = f2bf(acc[i][j][r]);
        } else {
            unsigned short* dst = sect ? kfm : qfm;
            const float scl = sect ? 1.f : FA_SCL2;
            const size_t cb = ((size_t)blockIdx.x * 16 + (ncol >> 3)) * 512 + (ncol & 7);
            #pragma unroll
            for (int i = 0; i < 4; ++i)
                #pragma unroll
                for (int r = 0; r < 4; ++r)
                    dst[cb + (size_t)(i * 16 + quad * 4 + r) * 8]
                        = f2bf(acc[i][j][r] * scl);
        }
    }
}

// ---------------------------------------------------------------------------
// V plain -> Vfm: per (b, 64-key tile). grid 256 x 256 thr. (unchanged)
// ---------------------------------------------------------------------------
__global__ __launch_bounds__(256)
void transpose_v(const unsigned short* __restrict__ V, unsigned short* __restrict__ Vfm)
{
    __shared__ unsigned short T[128 * 72];   // [d][key-rel], stride 72
    const int tid = threadIdx.x;
    const int b  = blockIdx.x >> 6;
    const int kt = blockIdx.x & 63;
    const unsigned short* src = V + ((size_t)b * 4096 + kt * 64) * 128;
    #pragma unroll
    for (int i = 0; i < 4; ++i) {
        const int idx = tid + i * 256;
        const int key = idx >> 4, c8 = (idx & 15) * 8;
        bf16x8 d = *(const bf16x8*)(src + key * 128 + c8);
        #pragma unroll
        for (int e = 0; e < 8; ++e) T[(c8 + e) * 72 + key] = (unsigned short)d[e];
    }
    __syncthreads();
    unsigned short* dst = Vfm + (size_t)(b * 64 + kt) * 8192;
    #pragma unroll
    for (int i = 0; i < 4; ++i) {
        const int o = tid + i * 256;
        const int d = o & 127, c = o >> 7;
        bf16x8 x = *(const bf16x8*)&T[d * 72 + c * 8];
        *(bf16x8*)(dst + ((size_t)c * 128 + d) * 8) = x;
    }
}

// ---------------------------------------------------------------------------
// Flash attention v6: 512 thr (8 waves), Br=128 (2 q-tiles), Bc=64.
// Batch b pinned to XCDs {2b,2b+1} (K/V 2 MB/batch -> L2-resident).
// K/V double-buffered gl2lds (vmcnt(4) steady). KV-split x4.
// LDS 80 KB -> 2 blocks/CU (16 waves/CU).
// ---------------------------------------------------------------------------
__global__ __launch_bounds__(512)
void flash_attn3(const unsigned short* __restrict__ Qfm, const unsigned short* __restrict__ Kfm,
                 const unsigned short* __restrict__ Vfm,
                 unsigned short* __restrict__ Opart, float* __restrict__ Ml)
{
    __shared__ unsigned short Klds[2][8192];    // 2 x 16 KB (Q stages both)
    __shared__ unsigned short Vlds[2][8192];    // 2 x 16 KB
    __shared__ unsigned short Plds[8][1024];    // per-wave P (A-frag), 16 KB

    const int tid = threadIdx.x;
    const int wv = tid >> 6, lane = tid & 63;
    const int lm = lane & 15, quad = lane >> 4;

    // XCD-pinned decode: hw maps wg->XCD as blockIdx%8
    const int bx = blockIdx.x;
    const int xcd = bx & 7;
    const int b   = xcd >> 1;                    // batch on XCD pair {2b,2b+1}
    const int r   = (bx >> 3) * 2 + (xcd & 1);   // [0,128) per batch
    const int sp  = r & 3;
    const int qi2 = r >> 2;                      // [0,32)
    const int Qi  = (qi2 & 1) ? (qi2 >> 1) : (31 - (qi2 >> 1));  // heavy first
    const int n   = 2 * Qi + 2;                  // key tiles for this Q-block
    const int cnt = (n >> 2) + ((sp < (n & 3)) ? 1 : 0);
    const int ktb = sp * (n >> 2) + ((sp < (n & 3)) ? sp : (n & 3));
    const int kte = ktb + cnt;
    const int qtw = 2 * Qi + (wv >> 2);          // wave's 64-row q-tile
    const int rw  = (wv & 3) * 16;               // wave's rows inside the tile

    const int qt0 = 2 * Qi;
    const size_t ob0 = (size_t)((b * 64 + qt0) * 4 + sp) * 8192;
    const size_t ob1 = ob0 + 4 * 8192;
    const int mlb0 = ((b * 64 + qt0) * 4 + sp) * 128, mlb1 = mlb0 + 512;

    if (cnt == 0) {                      // neutral partial (both tiles)
        bf16x8 z = {0, 0, 0, 0, 0, 0, 0, 0};
        #pragma unroll
        for (int t = 0; t < 2; ++t) {
            *(bf16x8*)&Opart[ob0 + (size_t)(tid + t * 512) * 8] = z;
            *(bf16x8*)&Opart[ob1 + (size_t)(tid + t * 512) * 8] = z;
        }
        if (tid < 64) { Ml[mlb0 + tid] = -INFINITY; Ml[mlb1 + tid] = -INFINITY; }
        else if (tid < 128) { Ml[mlb0 + tid] = 0.f; Ml[mlb1 + tid] = 0.f; }
        return;
    }

    // stage both Q tiles (32 KB) into Klds[0..1], pull frags to regs
    {
        const size_t qb = (size_t)(b * 64 + qt0) * 8192;   // 2 contiguous tiles
        #pragma unroll
        for (int i = 0; i < 4; ++i) {
            const int p = wv * 4 + i;            // [0,32) pieces of 1 KB
            gl2lds16(Qfm + qb + (size_t)p * 512 + lane * 8, &Klds[0][0] + p * 512);
        }
    }
    __syncthreads();
    bf16x8 qf[4];
    {
        const unsigned short* Qt = &Klds[wv >> 2][0];
        #pragma unroll
        for (int c = 0; c < 4; ++c)
            qf[c] = *(const bf16x8*)&Qt[((c * 4 + quad) * 64 + rw + lm) * 8];
    }
    asm volatile("s_waitcnt lgkmcnt(0)" ::: "memory");   // qf secured
    __builtin_amdgcn_s_barrier();

    // prologue: first K/V tile -> buf 0 (overwrites Q: safe)
    {
        const size_t kb = (size_t)(b * 64 + ktb) * 8192;
        #pragma unroll
        for (int i = 0; i < 2; ++i) {
            const int pc = wv * 2 + i;
            gl2lds16(Kfm + kb + pc * 512 + lane * 8, &Klds[0][pc * 512]);
            gl2lds16(Vfm + kb + pc * 512 + lane * 8, &Vlds[0][pc * 512]);
        }
    }

    f32x4 oacc[8];
    #pragma unroll
    for (int oc = 0; oc < 8; ++oc) oacc[oc] = f32x4{0.f, 0.f, 0.f, 0.f};
    f32x4 m4 = f32x4{-INFINITY, -INFINITY, -INFINITY, -INFINITY};
    f32x4 l4 = f32x4{0.f, 0.f, 0.f, 0.f};
    unsigned short* Pw = Plds[wv];

    int cur = 0;
    for (int kt = ktb; kt < kte; ++kt) {
        __builtin_amdgcn_s_barrier();    // B1: buf[cur^1] free to overwrite
        if (kt + 1 < kte) {
            const size_t kb = (size_t)(b * 64 + kt + 1) * 8192;
            #pragma unroll
            for (int i = 0; i < 2; ++i) {
                const int pc = wv * 2 + i;
                gl2lds16(Kfm + kb + pc * 512 + lane * 8, &Klds[cur ^ 1][pc * 512]);
                gl2lds16(Vfm + kb + pc * 512 + lane * 8, &Vlds[cur ^ 1][pc * 512]);
            }
            asm volatile("s_waitcnt vmcnt(4)" ::: "memory");  // tile kt done
        } else {
            asm volatile("s_waitcnt vmcnt(0)" ::: "memory");
        }
        __builtin_amdgcn_s_barrier();    // B2: buf[cur] ready
        const unsigned short* Kc = &Klds[cur][0];
        const unsigned short* Vc = &Vlds[cur][0];

        // S = Q K^T (Q pre-scaled, base-2)
        f32x4 sv[4];
        __builtin_amdgcn_s_setprio(1);
        #pragma unroll
        for (int ct = 0; ct < 4; ++ct) {
            f32x4 a = f32x4{0.f, 0.f, 0.f, 0.f};
            #pragma unroll
            for (int c = 0; c < 4; ++c) {
                bf16x8 kf = *(const bf16x8*)&Kc[((c * 4 + quad) * 64 + ct * 16 + lm) * 8];
                a = mfma16(qf[c], kf, a);
            }
            sv[ct] = a;
        }
        __builtin_amdgcn_s_setprio(0);
        if (kt > qtw) {                  // tile fully above diagonal (low waves)
            #pragma unroll
            for (int ct = 0; ct < 4; ++ct)
                sv[ct] = f32x4{-INFINITY, -INFINITY, -INFINITY, -INFINITY};
        } else if (kt == qtw) {          // diagonal tile: mask key > row
            #pragma unroll
            for (int ct = 0; ct < 4; ++ct) {
                const int dg = ct * 16 + lm - rw - quad * 4;
                #pragma unroll
                for (int rr = 0; rr < 4; ++rr)
                    if (dg > rr) sv[ct][rr] = -INFINITY;
            }
        }
        // online softmax, base 2, with all-masked clamp
        f32x4 rmax = vmax4(vmax4(sv[0], sv[1]), vmax4(sv[2], sv[3]));
        #pragma unroll
        for (int d = 1; d < 16; d <<= 1) {
            f32x4 o;
            #pragma unroll
            for (int e = 0; e < 4; ++e) o[e] = __shfl_xor(rmax[e], d);
            rmax = vmax4(rmax, o);
        }
        const f32x4 mnew = vmax4(m4, rmax);
        const f32x4 msafe = vmax4(mnew, f32x4{-1e30f, -1e30f, -1e30f, -1e30f});
        f32x4 alpha, rs = f32x4{0.f, 0.f, 0.f, 0.f};
        #pragma unroll
        for (int e = 0; e < 4; ++e) alpha[e] = __builtin_amdgcn_exp2f(m4[e] - msafe[e]);
        #pragma unroll
        for (int ct = 0; ct < 4; ++ct)
            #pragma unroll
            for (int rr = 0; rr < 4; ++rr) {
                const float p = __builtin_amdgcn_exp2f(sv[ct][rr] - msafe[rr]);
                sv[ct][rr] = p; rs[rr] += p;
            }
        #pragma unroll
        for (int d = 1; d < 16; d <<= 1) {
            f32x4 o;
            #pragma unroll
            for (int e = 0; e < 4; ++e) o[e] = __shfl_xor(rs[e], d);
            rs += o;
        }
        l4 = l4 * alpha + rs;
        m4 = mnew;
        // P -> wave-private LDS (A-frag layout)
        #pragma unroll
        for (int ct = 0; ct < 4; ++ct) {
            const int cb = ((ct * 2 + (lm >> 3)) * 16 + quad * 4) * 8 + (lm & 7);
            #pragma unroll
            for (int rr = 0; rr < 4; ++rr)
                Pw[cb + rr * 8] = f2bf(sv[ct][rr]);
        }
        #pragma unroll
        for (int oc = 0; oc < 8; ++oc) oacc[oc] *= alpha;
        // O += P V
        __builtin_amdgcn_s_setprio(1);
        #pragma unroll
        for (int s = 0; s < 2; ++s) {
            bf16x8 pf = *(const bf16x8*)&Pw[((s * 4 + quad) * 16 + lm) * 8];
            #pragma unroll
            for (int oc = 0; oc < 8; ++oc) {
                bf16x8 vf = *(const bf16x8*)&Vc[((s * 4 + quad) * 128 + oc * 16 + lm) * 8];
                oacc[oc] = mfma16(pf, vf, oacc[oc]);
            }
        }
        __builtin_amdgcn_s_setprio(0);
        cur ^= 1;
    }

    // epilogue: per-wave 64-row tile qtw, rows rw..rw+15
    const size_t obw = (size_t)((b * 64 + qtw) * 4 + sp) * 8192;
    const int mlw = ((b * 64 + qtw) * 4 + sp) * 128;
    #pragma unroll
    for (int oc = 0; oc < 8; ++oc) {
        const size_t cb = obw + (size_t)((oc * 2 + (lm >> 3)) * 64
                          + rw + quad * 4) * 8 + (lm & 7);
        #pragma unroll
        for (int rr = 0; rr < 4; ++rr)
            Opart[cb + rr * 8] = f2bf(oacc[oc][rr]);
    }
    if (lm == 0)
        #pragma unroll
        for (int rr = 0; rr < 4; ++rr) {
            const int row = rw + quad * 4 + rr;
            Ml[mlw + row] = m4[rr];
            Ml[mlw + 64 + row] = l4[rr];
        }
}

// ---------------------------------------------------------------------------
// Merge 4 splits -> Ofm. grid 256 x 256 thr. (unchanged; base-2 m/l)
// ---------------------------------------------------------------------------
__global__ __launch_bounds__(256)
void fa_combine(const unsigned short* __restrict__ Opart, const float* __restrict__ Ml,
                unsigned short* __restrict__ Ofm)
{
    const int bq = blockIdx.x;
    const int tid = threadIdx.x;
    const size_t pbase = (size_t)bq * 4 * 8192;
    const int mlb = bq * 4 * 128;
    #pragma unroll
    for (int t = 0; t < 4; ++t) {
        const int g = tid + t * 256;
        const int r = g & 63;
        float m[4], l[4];
        #pragma unroll
        for (int s = 0; s < 4; ++s) {
            m[s] = Ml[mlb + s * 128 + r];
            l[s] = Ml[mlb + s * 128 + 64 + r];
        }
        const float M = fmaxf(fmaxf(m[0], m[1]), fmaxf(m[2], m[3]));
        float a[4], den = 0.f;
        #pragma unroll
        for (int s = 0; s < 4; ++s) {
            a[s] = __builtin_amdgcn_exp2f(m[s] - M);
            den += a[s] * l[s];
        }
        const float rsc = 1.f / den;
        float acc[8] = {};
        #pragma unroll
        for (int s = 0; s < 4; ++s) {
            bf16x8 x = *(const bf16x8*)&Opart[pbase + (size_t)s * 8192 + (size_t)g * 8];
            #pragma unroll
            for (int e = 0; e < 8; ++e) acc[e] += a[s] * bf2f((unsigned short)x[e]);
        }
        bf16x8 o;
        #pragma unroll
        for (int e = 0; e < 8; ++e) o[e] = f2bf(acc[e] * rsc);
        *(bf16x8*)&Ofm[(size_t)bq * 8192 + (size_t)g * 8] = o;
    }
}

// ---------------------------------------------------------------------------
// Output projection + bias. A from Ofm, B from Wofm (both gl2lds).
// grid(128,8) x 256 thr. A double-buffered, raw barriers.
// ---------------------------------------------------------------------------
__global__ __launch_bounds__(256)
void gemm_out(const unsigned short* __restrict__ Ain, const unsigned short* __restrict__ Wofm,
              const float* __restrict__ bias, float* __restrict__ out)
{
    __shared__ unsigned short Bsl[16384];      // 32 KB: piece p=(tl*16+c)
    __shared__ unsigned short Asl[2][4096];    // 2 x 8 KB
    const int tid = threadIdx.x;
    const int mb = blockIdx.x * 128;
    const int nb = blockIdx.y * 128;
    const int wv = tid >> 6, lane = tid & 63;
    const int wr = (wv >> 1) * 64, wc = (wv & 1) * 64;
    const int lm = lane & 15, quad = lane >> 4;

    // stage W tile (32 KB, 32 pieces) + A(0)
    #pragma unroll
    for (int i = 0; i < 8; ++i) {
        const int p = wv * 8 + i;
        gl2lds16(Wofm + (size_t)(((nb >> 6) + (p >> 4)) * 16 + (p & 15)) * 512 + lane * 8,
                 &Bsl[p * 512]);
    }
    #pragma unroll
    for (int i = 0; i < 2; ++i) {
        const int id = wv * 2 + i, t = id >> 2, kcl = id & 3;
        gl2lds16(Ain + (size_t)((mb >> 6) + t) * 8192 + kcl * 512 + lane * 8,
                 &Asl[0][(t * 4 + kcl) * 512]);
    }

    f32x4 acc[4][4];
    #pragma unroll
    for (int i = 0; i < 4; ++i)
        #pragma unroll
        for (int j = 0; j < 4; ++j) acc[i][j] = f32x4{0.f, 0.f, 0.f, 0.f};

    for (int kt = 0; kt < 4; ++kt) {
        __builtin_amdgcn_s_barrier();
        if (kt < 3) {
            #pragma unroll
            for (int i = 0; i < 2; ++i) {
                const int id = wv * 2 + i, t = id >> 2, kcl = id & 3;
                gl2lds16(Ain + (size_t)((mb >> 6) + t) * 8192 + ((kt + 1) * 4 + kcl) * 512 + lane * 8,
                         &Asl[(kt + 1) & 1][(t * 4 + kcl) * 512]);
            }
            asm volatile("s_waitcnt vmcnt(2)" ::: "memory");
        } else {
            asm volatile("s_waitcnt vmcnt(0)" ::: "memory");
        }
        __builtin_amdgcn_s_barrier();
        const unsigned short* Ac = Asl[kt & 1];
        bf16x8 af[4], bfr[4];
        #pragma unroll
        for (int i = 0; i < 4; ++i)
            af[i] = *(const bf16x8*)&Ac[(((wv >> 1) * 4 + quad) * 64 + i * 16 + lm) * 8];
        #pragma unroll
        for (int j = 0; j < 4; ++j)
            bfr[j] = *(const bf16x8*)&Bsl[(((wc >> 6) * 16 + kt * 4 + quad) * 64 + j * 16 + lm) * 8];
        #pragma unroll
        for (int i = 0; i < 4; ++i)
            #pragma unroll
            for (int j = 0; j < 4; ++j)
                acc[i][j] = mfma16(af[i], bfr[j], acc[i][j]);
    }

    #pragma unroll
    for (int j = 0; j < 4; ++j) {
        const int col = nb + wc + j * 16 + lm;
        const float bv = bias[col];
        #pragma unroll
        for (int i = 0; i < 4; ++i)
            #pragma unroll
            for (int r = 0; r < 4; ++r) {
                const int m = mb + wr + i * 16 + quad * 4 + r;
                out[(size_t)m * 1024 + col] = acc[i][j][r] + bv;
            }
    }
}

// ---------------------------------------------------------------------------
extern "C" void kernel_launch(void* const* d_in, const int* in_sizes, int n_in,
                              void* d_out, int out_size, void* d_ws, size_t ws_size,
                              hipStream_t stream)
{
    (void)in_sizes; (void)n_in; (void)out_size; (void)ws_size;
    const float* x     = (const float*)d_in[0];
    const float* w_qkv = (const float*)d_in[1];
    const float* w_out = (const float*)d_in[2];
    const float* b_out = (const float*)d_in[3];
    float* out = (float*)d_out;
    unsigned short* ws = (unsigned short*)d_ws;

    const size_t NE = (size_t)16384 * 128;          // 2 097 152
    unsigned short* qfm = ws;                        // 4 MB (Ofm aliases after flash)
    unsigned short* kfm = ws + NE;                   // 4 MB
    unsigned short* vpl = ws + 2 * NE;               // 4 MB
    unsigned short* vfm = ws + 3 * NE;               // 4 MB
    unsigned short* op  = ws + 4 * NE;               // Opart 16.8 MB
    float*          ml  = (float*)(ws + 8 * NE);     // 0.5 MB
    unsigned short* ofm = qfm;                       // alias: Qfm dead after flash
    unsigned short* wfm = op;                        // alias: dead before flash
    unsigned short* wofm = vpl;                      // alias: vpl dead after transpose_v

    hipLaunchKernelGGL(wcast,       dim3(192),    dim3(256), 0, stream, w_qkv, wfm);
    hipLaunchKernelGGL(gemm_qkv,    dim3(256),    dim3(512), 0, stream, x, wfm, qfm, kfm, vpl);
    hipLaunchKernelGGL(transpose_v, dim3(256),    dim3(256), 0, stream, vpl, vfm);
    hipLaunchKernelGGL(woutcast,    dim3(64),     dim3(256), 0, stream, w_out, wofm);
    hipLaunchKernelGGL(flash_attn3, dim3(512),    dim3(512), 0, stream, qfm, kfm, vfm, op, ml);
    hipLaunchKernelGGL(fa_combine,  dim3(256),    dim3(256), 0, stream, op, ml, ofm);
    hipLaunchKernelGGL(gemm_out,    dim3(128, 8), dim3(256), 0, stream, ofm, wofm, b_out, out);
}

// Round 3
// 198.223 us; speedup vs baseline: 1.1651x; 1.1111x over previous
//
#include <hip/hip_runtime.h>
#include <math.h>

// ---------------------------------------------------------------------------
// bf16-MFMA pipeline v7:
//   wcast       : w_qkv fp32 -> Wfm frag-major bf16 (once)
//   gemm_qkv    : fused QKV, X read once; A reg-prefetch now 2-deep (HBM
//                 latency cover), B triple-buffered gl2lds
//   transpose_v : V plain -> Vfm (unchanged)
//   woutcast    : w_out fp32 -> Wofm frag-major bf16
//   flash_attn3 : balanced heavy+light CU pairing; sum-butterfly replaced by
//                 ones-column MFMA; defer-max (THR=8); masked-tile skip
//   fa_combine  : unchanged
//   gemm_out    : unchanged
// Layout: addr(tile,c,r,j) = ((tile*NC + c)*64 + r)*8 + j  (NC = K/8)
// ---------------------------------------------------------------------------

typedef __attribute__((ext_vector_type(8))) short bf16x8;
typedef __attribute__((ext_vector_type(4))) short bf16x4;
typedef __attribute__((ext_vector_type(4))) float f32x4;

#define FA_SCL2 0.12751886525137387f   // 128^-0.5 * log2(e)

__device__ __forceinline__ unsigned short f2bf(float f) {
    __bf16 h = (__bf16)f;                       // native cvt (RNE)
    return __builtin_bit_cast(unsigned short, h);
}
__device__ __forceinline__ float bf2f(unsigned short h) {
    union { unsigned u; float f; } v; v.u = ((unsigned)h) << 16;
    return v.f;
}
__device__ __forceinline__ f32x4 mfma16(bf16x8 a, bf16x8 b, f32x4 c) {
    return __builtin_amdgcn_mfma_f32_16x16x32_bf16(a, b, c, 0, 0, 0);
}
__device__ __forceinline__ void gl2lds16(const void* g, void* l) {
    __builtin_amdgcn_global_load_lds(
        (const __attribute__((address_space(1))) unsigned int*)g,
        (__attribute__((address_space(3))) unsigned int*)l, 16, 0, 0);
}
__device__ __forceinline__ f32x4 vmax4(f32x4 a, f32x4 b) {
    return f32x4{fmaxf(a[0], b[0]), fmaxf(a[1], b[1]),
                 fmaxf(a[2], b[2]), fmaxf(a[3], b[3])};
}

// ---------------------------------------------------------------------------
// W fp32 [384][1024] -> frag-major bf16. grid 192 x 256 thr.
// ---------------------------------------------------------------------------
__global__ __launch_bounds__(256)
void wcast(const float* __restrict__ W, unsigned short* __restrict__ wfm)
{
    const int idx = blockIdx.x * 256 + threadIdx.x;   // 49152 granules
    const int kc = idx & 127, r = idx >> 7;
    const float* g = W + (size_t)r * 1024 + kc * 8;
    float4 w0 = *(const float4*)g, w1 = *(const float4*)(g + 4);
    bf16x8 p;
    p[0] = (short)f2bf(w0.x); p[1] = (short)f2bf(w0.y);
    p[2] = (short)f2bf(w0.z); p[3] = (short)f2bf(w0.w);
    p[4] = (short)f2bf(w1.x); p[5] = (short)f2bf(w1.y);
    p[6] = (short)f2bf(w1.z); p[7] = (short)f2bf(w1.w);
    *(bf16x8*)&wfm[(size_t)(kc * 384 + r) * 8] = p;
}

// ---------------------------------------------------------------------------
// w_out fp32 [1024][128] -> frag-major bf16 64-row tiles. grid 64 x 256 thr.
// ---------------------------------------------------------------------------
__global__ __launch_bounds__(256)
void woutcast(const float* __restrict__ W, unsigned short* __restrict__ wofm)
{
    const int idx = blockIdx.x * 256 + threadIdx.x;   // 16384 granules
    const int c = idx & 15, rg = idx >> 4;            // rg in [0,1024)
    const float* g = W + (size_t)rg * 128 + c * 8;
    float4 w0 = *(const float4*)g, w1 = *(const float4*)(g + 4);
    bf16x8 p;
    p[0] = (short)f2bf(w0.x); p[1] = (short)f2bf(w0.y);
    p[2] = (short)f2bf(w0.z); p[3] = (short)f2bf(w0.w);
    p[4] = (short)f2bf(w1.x); p[5] = (short)f2bf(w1.y);
    p[6] = (short)f2bf(w1.z); p[7] = (short)f2bf(w1.w);
    *(bf16x8*)&wofm[((size_t)((rg >> 6) * 16 + c) * 64 + (rg & 63)) * 8] = p;
}

// ---------------------------------------------------------------------------
// Fused QKV projection. BM=64, BN=384, BK=32. grid 256 x 512 thr.
// A prefetch 2 tiles deep (HBM latency), B triple-buffered gl2lds.
// ---------------------------------------------------------------------------
__global__ __launch_bounds__(512)
void gemm_qkv(const float* __restrict__ X, const unsigned short* __restrict__ Wfm,
              unsigned short* __restrict__ qfm, unsigned short* __restrict__ kfm,
              unsigned short* __restrict__ vpl)
{
    __shared__ unsigned short Asl[2048];          // 4 KB frag-major A (64x32)
    __shared__ unsigned short Bsl[3][12288];      // 3 x 24 KB (384x32)
    const int tid = threadIdx.x;
    const int wv = tid >> 6, lane = tid & 63;
    const int lm = lane & 15, quad = lane >> 4;
    const int mb = blockIdx.x * 64;
    const int arow = tid >> 3, af4 = tid & 7;     // A staging: row, float4 idx

    f32x4 acc[4][3];
    #pragma unroll
    for (int i = 0; i < 4; ++i)
        #pragma unroll
        for (int j = 0; j < 3; ++j) acc[i][j] = f32x4{0.f, 0.f, 0.f, 0.f};

    const float* gx = X + (size_t)(mb + arow) * 1024 + af4 * 4;

    // B staging: 24 pieces of 1 KB; wave wv stages pieces wv*3 + {0,1,2}
    auto issueB = [&](int it, int buf) {
        #pragma unroll
        for (int i = 0; i < 3; ++i) {
            const int p = wv * 3 + i;
            const int kcl = p & 3, rg = p >> 2;
            gl2lds16(Wfm + (size_t)((it * 4 + kcl) * 384 + rg * 64) * 8 + lane * 8,
                     &Bsl[buf][(kcl * 384 + rg * 64) * 8]);
        }
    };

    // prologue: A(0), B(0), A(1), B(1) in flight (invariant: 14 outstanding)
    float4 f0 = *(const float4*)gx;
    issueB(0, 0);
    float4 f1 = *(const float4*)(gx + 32);
    issueB(1, 1);

    auto step = [&](const int i, float4& f) {
        __builtin_amdgcn_s_barrier();             // B1: Asl/Bsl[(i+2)%3] free
        {   // A(i) regs -> LDS (compiler waits vmcnt for f = A(i))
            bf16x4 pk;
            pk[0] = (short)f2bf(f.x); pk[1] = (short)f2bf(f.y);
            pk[2] = (short)f2bf(f.z); pk[3] = (short)f2bf(f.w);
            *(bf16x4*)&Asl[((af4 >> 1) * 64 + arow) * 8 + (af4 & 1) * 4] = pk;
        }
        if (i < 30) {
            f = *(const float4*)(gx + (i + 2) * 32);   // A(i+2), 2-iter slack
            issueB(i + 2, (i + 2) % 3);
            asm volatile("s_waitcnt vmcnt(14) lgkmcnt(0)" ::: "memory"); // B(i) done
        } else if (i == 30) {
            asm volatile("s_waitcnt vmcnt(7) lgkmcnt(0)" ::: "memory");  // B(30) done
        } else {
            asm volatile("s_waitcnt vmcnt(0) lgkmcnt(0)" ::: "memory");
        }
        __builtin_amdgcn_s_barrier();             // B2: tile i ready
        const unsigned short* Bc = Bsl[i % 3];
        bf16x8 afr[4], bfr[3];
        #pragma unroll
        for (int i4 = 0; i4 < 4; ++i4)
            afr[i4] = *(const bf16x8*)&Asl[(quad * 64 + i4 * 16 + lm) * 8];
        #pragma unroll
        for (int j = 0; j < 3; ++j)
            bfr[j] = *(const bf16x8*)&Bc[(quad * 384 + wv * 48 + j * 16 + lm) * 8];
        #pragma unroll
        for (int i4 = 0; i4 < 4; ++i4)
            #pragma unroll
            for (int j = 0; j < 3; ++j)
                acc[i4][j] = mfma16(afr[i4], bfr[j], acc[i4][j]);
    };

    for (int p = 0; p < 16; ++p) { step(2 * p, f0); step(2 * p + 1, f1); }

    // epilogue: cols 0-127 -> Q (scaled), 128-255 -> K, 256-383 -> V plain
    #pragma unroll
    for (int j = 0; j < 3; ++j) {
        const int ncg = wv * 48 + j * 16 + lm;    // frag never straddles 128
        const int sect = ncg >> 7, ncol = ncg & 127;
        if (sect == 2) {
            #pragma unroll
            for (int i = 0; i < 4; ++i)
                #pragma unroll
                for (int r = 0; r < 4; ++r)
                    vpl[(size_t)(mb + i * 16 + quad * 4 + r) * 128 + ncol]
                        = f2bf(acc[i][j][r]);
        } else {
            unsigned short* dst = sect ? kfm : qfm;
            const float scl = sect ? 1.f : FA_SCL2;
            const size_t cb = ((size_t)blockIdx.x * 16 + (ncol >> 3)) * 512 + (ncol & 7);
            #pragma unroll
            for (int i = 0; i < 4; ++i)
                #pragma unroll
                for (int r = 0; r < 4; ++r)
                    dst[cb + (size_t)(i * 16 + quad * 4 + r) * 8]
                        = f2bf(acc[i][j][r] * scl);
        }
    }
}

// ---------------------------------------------------------------------------
// V plain -> Vfm. grid 256 x 256 thr. (unchanged)
// ---------------------------------------------------------------------------
__global__ __launch_bounds__(256)
void transpose_v(const unsigned short* __restrict__ V, unsigned short* __restrict__ Vfm)
{
    __shared__ unsigned short T[128 * 72];   // [d][key-rel], stride 72
    const int tid = threadIdx.x;
    const int b  = blockIdx.x >> 6;
    const int kt = blockIdx.x & 63;
    const unsigned short* src = V + ((size_t)b * 4096 + kt * 64) * 128;
    #pragma unroll
    for (int i = 0; i < 4; ++i) {
        const int idx = tid + i * 256;
        const int key = idx >> 4, c8 = (idx & 15) * 8;
        bf16x8 d = *(const bf16x8*)(src + key * 128 + c8);
        #pragma unroll
        for (int e = 0; e < 8; ++e) T[(c8 + e) * 72 + key] = (unsigned short)d[e];
    }
    __syncthreads();
    unsigned short* dst = Vfm + (size_t)(b * 64 + kt) * 8192;
    #pragma unroll
    for (int i = 0; i < 4; ++i) {
        const int o = tid + i * 256;
        const int d = o & 127, c = o >> 7;
        bf16x8 x = *(const bf16x8*)&T[d * 72 + c * 8];
        *(bf16x8*)(dst + ((size_t)c * 128 + d) * 8) = x;
    }
}

// ---------------------------------------------------------------------------
// Flash attention v7: 512 thr (8 waves), Br=128, Bc=64. Balanced mapping:
// heavy (Qi 16-31) blocks are bx<256 (one per CU, start first), light fill
// second slots -> per-CU load ~16.5 iters. Sum-butterfly removed (ones-col
// MFMA). Defer-max THR=8. Masked-tile skip. LDS 80 KB -> 2 blocks/CU.
// ---------------------------------------------------------------------------
__global__ __launch_bounds__(512)
void flash_attn3(const unsigned short* __restrict__ Qfm, const unsigned short* __restrict__ Kfm,
                 const unsigned short* __restrict__ Vfm,
                 unsigned short* __restrict__ Opart, float* __restrict__ Ml)
{
    __shared__ unsigned short Klds[2][8192];    // 2 x 16 KB (Q stages both)
    __shared__ unsigned short Vlds[2][8192];    // 2 x 16 KB
    __shared__ unsigned short Plds[8][1024];    // per-wave P (A-frag), 16 KB

    const int tid = threadIdx.x;
    const int wv = tid >> 6, lane = tid & 63;
    const int lm = lane & 15, quad = lane >> 4;

    // XCD-pinned, load-balanced decode (heavy blocks first)
    const int bx = blockIdx.x;
    const int xcd = bx & 7;
    const int b   = xcd >> 1;                    // batch on XCD pair {2b,2b+1}
    const int r   = (bx >> 3) * 2 + (xcd & 1);   // [0,128) per batch
    const int sp  = r & 3;
    const int Qi  = (r < 64) ? (16 + (r >> 2)) : (15 - ((r - 64) >> 2));
    const int n   = 2 * Qi + 2;                  // key tiles for this Q-block
    const int cnt = (n >> 2) + ((sp < (n & 3)) ? 1 : 0);
    const int ktb = sp * (n >> 2) + ((sp < (n & 3)) ? sp : (n & 3));
    const int kte = ktb + cnt;
    const int qtw = 2 * Qi + (wv >> 2);          // wave's 64-row q-tile
    const int rw  = (wv & 3) * 16;               // wave's rows inside the tile

    const int qt0 = 2 * Qi;
    const size_t ob0 = (size_t)((b * 64 + qt0) * 4 + sp) * 8192;
    const size_t ob1 = ob0 + 4 * 8192;
    const int mlb0 = ((b * 64 + qt0) * 4 + sp) * 128, mlb1 = mlb0 + 512;

    if (cnt == 0) {                      // neutral partial (both tiles)
        bf16x8 z = {0, 0, 0, 0, 0, 0, 0, 0};
        #pragma unroll
        for (int t = 0; t < 2; ++t) {
            *(bf16x8*)&Opart[ob0 + (size_t)(tid + t * 512) * 8] = z;
            *(bf16x8*)&Opart[ob1 + (size_t)(tid + t * 512) * 8] = z;
        }
        if (tid < 64) { Ml[mlb0 + tid] = -INFINITY; Ml[mlb1 + tid] = -INFINITY; }
        else if (tid < 128) { Ml[mlb0 + tid] = 0.f; Ml[mlb1 + tid] = 0.f; }
        return;
    }

    // stage both Q tiles (32 KB), pull frags to regs
    {
        const size_t qb = (size_t)(b * 64 + qt0) * 8192;
        #pragma unroll
        for (int i = 0; i < 4; ++i) {
            const int p = wv * 4 + i;
            gl2lds16(Qfm + qb + (size_t)p * 512 + lane * 8, &Klds[0][0] + p * 512);
        }
    }
    __syncthreads();
    bf16x8 qf[4];
    {
        const unsigned short* Qt = &Klds[wv >> 2][0];
        #pragma unroll
        for (int c = 0; c < 4; ++c)
            qf[c] = *(const bf16x8*)&Qt[((c * 4 + quad) * 64 + rw + lm) * 8];
    }
    asm volatile("s_waitcnt lgkmcnt(0)" ::: "memory");   // qf secured
    __builtin_amdgcn_s_barrier();

    // prologue: first K/V tile -> buf 0 (overwrites Q: safe)
    {
        const size_t kb = (size_t)(b * 64 + ktb) * 8192;
        #pragma unroll
        for (int i = 0; i < 2; ++i) {
            const int pc = wv * 2 + i;
            gl2lds16(Kfm + kb + pc * 512 + lane * 8, &Klds[0][pc * 512]);
            gl2lds16(Vfm + kb + pc * 512 + lane * 8, &Vlds[0][pc * 512]);
        }
    }

    f32x4 oacc[8];
    #pragma unroll
    for (int oc = 0; oc < 8; ++oc) oacc[oc] = f32x4{0.f, 0.f, 0.f, 0.f};
    f32x4 m4 = f32x4{-INFINITY, -INFINITY, -INFINITY, -INFINITY};
    f32x4 lacc = f32x4{0.f, 0.f, 0.f, 0.f};
    unsigned short* Pw = Plds[wv];
    const short ONE = (short)0x3F80;             // bf16 1.0
    const bf16x8 ONESB = {ONE, ONE, ONE, ONE, ONE, ONE, ONE, ONE};

    for (int kt = ktb; kt < kte; ++kt) {
        const int cu = (kt - ktb) & 1;
        __builtin_amdgcn_s_barrier();    // B1: buf[cu^1] free to overwrite
        if (kt + 1 < kte) {
            const size_t kb = (size_t)(b * 64 + kt + 1) * 8192;
            #pragma unroll
            for (int i = 0; i < 2; ++i) {
                const int pc = wv * 2 + i;
                gl2lds16(Kfm + kb + pc * 512 + lane * 8, &Klds[cu ^ 1][pc * 512]);
                gl2lds16(Vfm + kb + pc * 512 + lane * 8, &Vlds[cu ^ 1][pc * 512]);
            }
            asm volatile("s_waitcnt vmcnt(4)" ::: "memory");  // tile kt done
        } else {
            asm volatile("s_waitcnt vmcnt(0)" ::: "memory");
        }
        __builtin_amdgcn_s_barrier();    // B2: buf[cu] ready
        if (kt > qtw) continue;          // wave's rows fully masked this tile

        const unsigned short* Kc = &Klds[cu][0];
        const unsigned short* Vc = &Vlds[cu][0];

        // S = Q K^T (Q pre-scaled to base-2)
        f32x4 sv[4];
        __builtin_amdgcn_s_setprio(1);
        #pragma unroll
        for (int ct = 0; ct < 4; ++ct) {
            f32x4 a = f32x4{0.f, 0.f, 0.f, 0.f};
            #pragma unroll
            for (int c = 0; c < 4; ++c) {
                bf16x8 kf = *(const bf16x8*)&Kc[((c * 4 + quad) * 64 + ct * 16 + lm) * 8];
                a = mfma16(qf[c], kf, a);
            }
            sv[ct] = a;
        }
        __builtin_amdgcn_s_setprio(0);
        if (kt == qtw) {                 // diagonal tile: mask key > row
            #pragma unroll
            for (int ct = 0; ct < 4; ++ct) {
                const int dg = ct * 16 + lm - rw - quad * 4;
                #pragma unroll
                for (int rr = 0; rr < 4; ++rr)
                    if (dg > rr) sv[ct][rr] = -INFINITY;
            }
        }
        // defer-max online softmax (base 2). Local max is register-only;
        // cross-lane butterfly + rescale only when growth > 8.
        const f32x4 pmax = vmax4(vmax4(sv[0], sv[1]), vmax4(sv[2], sv[3]));
        const float dm = fmaxf(fmaxf(pmax[0] - m4[0], pmax[1] - m4[1]),
                               fmaxf(pmax[2] - m4[2], pmax[3] - m4[3]));
        if (!__all(dm <= 8.f)) {
            f32x4 rmax = pmax;
            #pragma unroll
            for (int d = 1; d < 16; d <<= 1) {
                f32x4 o;
                #pragma unroll
                for (int e = 0; e < 4; ++e) o[e] = __shfl_xor(rmax[e], d);
                rmax = vmax4(rmax, o);
            }
            const f32x4 mnew = vmax4(m4, rmax);       // finite here (diag row)
            f32x4 alpha;
            #pragma unroll
            for (int e = 0; e < 4; ++e) alpha[e] = __builtin_amdgcn_exp2f(m4[e] - mnew[e]);
            m4 = mnew;
            #pragma unroll
            for (int oc = 0; oc < 8; ++oc) oacc[oc] *= alpha;
            lacc *= alpha;
        }
        #pragma unroll
        for (int ct = 0; ct < 4; ++ct)
            #pragma unroll
            for (int rr = 0; rr < 4; ++rr)
                sv[ct][rr] = __builtin_amdgcn_exp2f(sv[ct][rr] - m4[rr]);
        // P -> wave-private LDS (A-frag layout)
        #pragma unroll
        for (int ct = 0; ct < 4; ++ct) {
            const int cb = ((ct * 2 + (lm >> 3)) * 16 + quad * 4) * 8 + (lm & 7);
            #pragma unroll
            for (int rr = 0; rr < 4; ++rr)
                Pw[cb + rr * 8] = f2bf(sv[ct][rr]);
        }
        // O += P V ; l += P 1  (row-sum via ones-column MFMA)
        __builtin_amdgcn_s_setprio(1);
        #pragma unroll
        for (int s = 0; s < 2; ++s) {
            bf16x8 pf = *(const bf16x8*)&Pw[((s * 4 + quad) * 16 + lm) * 8];
            lacc = mfma16(pf, ONESB, lacc);
            #pragma unroll
            for (int oc = 0; oc < 8; ++oc) {
                bf16x8 vf = *(const bf16x8*)&Vc[((s * 4 + quad) * 128 + oc * 16 + lm) * 8];
                oacc[oc] = mfma16(pf, vf, oacc[oc]);
            }
        }
        __builtin_amdgcn_s_setprio(0);
    }

    // epilogue: per-wave 64-row tile qtw, rows rw..rw+15
    const size_t obw = (size_t)((b * 64 + qtw) * 4 + sp) * 8192;
    const int mlw = ((b * 64 + qtw) * 4 + sp) * 128;
    #pragma unroll
    for (int oc = 0; oc < 8; ++oc) {
        const size_t cb = obw + (size_t)((oc * 2 + (lm >> 3)) * 64
                          + rw + quad * 4) * 8 + (lm & 7);
        #pragma unroll
        for (int rr = 0; rr < 4; ++rr)
            Opart[cb + rr * 8] = f2bf(oacc[oc][rr]);
    }
    if (lm == 0)
        #pragma unroll
        for (int rr = 0; rr < 4; ++rr) {
            const int row = rw + quad * 4 + rr;
            Ml[mlw + row] = m4[rr];
            Ml[mlw + 64 + row] = lacc[rr];
        }
}

// ---------------------------------------------------------------------------
// Merge 4 splits -> Ofm. grid 256 x 256 thr. (unchanged; base-2 m/l)
// ---------------------------------------------------------------------------
__global__ __launch_bounds__(256)
void fa_combine(const unsigned short* __restrict__ Opart, const float* __restrict__ Ml,
                unsigned short* __restrict__ Ofm)
{
    const int bq = blockIdx.x;
    const int tid = threadIdx.x;
    const size_t pbase = (size_t)bq * 4 * 8192;
    const int mlb = bq * 4 * 128;
    #pragma unroll
    for (int t = 0; t < 4; ++t) {
        const int g = tid + t * 256;
        const int r = g & 63;
        float m[4], l[4];
        #pragma unroll
        for (int s = 0; s < 4; ++s) {
            m[s] = Ml[mlb + s * 128 + r];
            l[s] = Ml[mlb + s * 128 + 64 + r];
        }
        const float M = fmaxf(fmaxf(m[0], m[1]), fmaxf(m[2], m[3]));
        float a[4], den = 0.f;
        #pragma unroll
        for (int s = 0; s < 4; ++s) {
            a[s] = __builtin_amdgcn_exp2f(m[s] - M);
            den += a[s] * l[s];
        }
        const float rsc = 1.f / den;
        float acc[8] = {};
        #pragma unroll
        for (int s = 0; s < 4; ++s) {
            bf16x8 x = *(const bf16x8*)&Opart[pbase + (size_t)s * 8192 + (size_t)g * 8];
            #pragma unroll
            for (int e = 0; e < 8; ++e) acc[e] += a[s] * bf2f((unsigned short)x[e]);
        }
        bf16x8 o;
        #pragma unroll
        for (int e = 0; e < 8; ++e) o[e] = f2bf(acc[e] * rsc);
        *(bf16x8*)&Ofm[(size_t)bq * 8192 + (size_t)g * 8] = o;
    }
}

// ---------------------------------------------------------------------------
// Output projection + bias. grid(128,8) x 256 thr. (unchanged)
// ---------------------------------------------------------------------------
__global__ __launch_bounds__(256)
void gemm_out(const unsigned short* __restrict__ Ain, const unsigned short* __restrict__ Wofm,
              const float* __restrict__ bias, float* __restrict__ out)
{
    __shared__ unsigned short Bsl[16384];      // 32 KB
    __shared__ unsigned short Asl[2][4096];    // 2 x 8 KB
    const int tid = threadIdx.x;
    const int mb = blockIdx.x * 128;
    const int nb = blockIdx.y * 128;
    const int wv = tid >> 6, lane = tid & 63;
    const int wr = (wv >> 1) * 64, wc = (wv & 1) * 64;
    const int lm = lane & 15, quad = lane >> 4;

    #pragma unroll
    for (int i = 0; i < 8; ++i) {
        const int p = wv * 8 + i;
        gl2lds16(Wofm + (size_t)(((nb >> 6) + (p >> 4)) * 16 + (p & 15)) * 512 + lane * 8,
                 &Bsl[p * 512]);
    }
    #pragma unroll
    for (int i = 0; i < 2; ++i) {
        const int id = wv * 2 + i, t = id >> 2, kcl = id & 3;
        gl2lds16(Ain + (size_t)((mb >> 6) + t) * 8192 + kcl * 512 + lane * 8,
                 &Asl[0][(t * 4 + kcl) * 512]);
    }

    f32x4 acc[4][4];
    #pragma unroll
    for (int i = 0; i < 4; ++i)
        #pragma unroll
        for (int j = 0; j < 4; ++j) acc[i][j] = f32x4{0.f, 0.f, 0.f, 0.f};

    for (int kt = 0; kt < 4; ++kt) {
        __builtin_amdgcn_s_barrier();
        if (kt < 3) {
            #pragma unroll
            for (int i = 0; i < 2; ++i) {
                const int id = wv * 2 + i, t = id >> 2, kcl = id & 3;
                gl2lds16(Ain + (size_t)((mb >> 6) + t) * 8192 + ((kt + 1) * 4 + kcl) * 512 + lane * 8,
                         &Asl[(kt + 1) & 1][(t * 4 + kcl) * 512]);
            }
            asm volatile("s_waitcnt vmcnt(2)" ::: "memory");
        } else {
            asm volatile("s_waitcnt vmcnt(0)" ::: "memory");
        }
        __builtin_amdgcn_s_barrier();
        const unsigned short* Ac = Asl[kt & 1];
        bf16x8 af[4], bfr[4];
        #pragma unroll
        for (int i = 0; i < 4; ++i)
            af[i] = *(const bf16x8*)&Ac[(((wv >> 1) * 4 + quad) * 64 + i * 16 + lm) * 8];
        #pragma unroll
        for (int j = 0; j < 4; ++j)
            bfr[j] = *(const bf16x8*)&Bsl[(((wc >> 6) * 16 + kt * 4 + quad) * 64 + j * 16 + lm) * 8];
        #pragma unroll
        for (int i = 0; i < 4; ++i)
            #pragma unroll
            for (int j = 0; j < 4; ++j)
                acc[i][j] = mfma16(af[i], bfr[j], acc[i][j]);
    }

    #pragma unroll
    for (int j = 0; j < 4; ++j) {
        const int col = nb + wc + j * 16 + lm;
        const float bv = bias[col];
        #pragma unroll
        for (int i = 0; i < 4; ++i)
            #pragma unroll
            for (int r = 0; r < 4; ++r) {
                const int m = mb + wr + i * 16 + quad * 4 + r;
                out[(size_t)m * 1024 + col] = acc[i][j][r] + bv;
            }
    }
}

// ---------------------------------------------------------------------------
extern "C" void kernel_launch(void* const* d_in, const int* in_sizes, int n_in,
                              void* d_out, int out_size, void* d_ws, size_t ws_size,
                              hipStream_t stream)
{
    (void)in_sizes; (void)n_in; (void)out_size; (void)ws_size;
    const float* x     = (const float*)d_in[0];
    const float* w_qkv = (const float*)d_in[1];
    const float* w_out = (const float*)d_in[2];
    const float* b_out = (const float*)d_in[3];
    float* out = (float*)d_out;
    unsigned short* ws = (unsigned short*)d_ws;

    const size_t NE = (size_t)16384 * 128;          // 2 097 152
    unsigned short* qfm = ws;                        // 4 MB (Ofm aliases after flash)
    unsigned short* kfm = ws + NE;                   // 4 MB
    unsigned short* vpl = ws + 2 * NE;               // 4 MB
    unsigned short* vfm = ws + 3 * NE;               // 4 MB
    unsigned short* op  = ws + 4 * NE;               // Opart 16.8 MB
    float*          ml  = (float*)(ws + 8 * NE);     // 0.5 MB
    unsigned short* ofm = qfm;                       // alias: Qfm dead after flash
    unsigned short* wfm = op;                        // alias: dead before flash
    unsigned short* wofm = vpl;                      // alias: vpl dead after transpose_v

    hipLaunchKernelGGL(wcast,       dim3(192),    dim3(256), 0, stream, w_qkv, wfm);
    hipLaunchKernelGGL(gemm_qkv,    dim3(256),    dim3(512), 0, stream, x, wfm, qfm, kfm, vpl);
    hipLaunchKernelGGL(transpose_v, dim3(256),    dim3(256), 0, stream, vpl, vfm);
    hipLaunchKernelGGL(woutcast,    dim3(64),     dim3(256), 0, stream, w_out, wofm);
    hipLaunchKernelGGL(flash_attn3, dim3(512),    dim3(512), 0, stream, qfm, kfm, vfm, op, ml);
    hipLaunchKernelGGL(fa_combine,  dim3(256),    dim3(256), 0, stream, op, ml, ofm);
    hipLaunchKernelGGL(gemm_out,    dim3(128, 8), dim3(256), 0, stream, ofm, wofm, b_out, out);
}

// Round 4
// 196.194 us; speedup vs baseline: 1.1772x; 1.0103x over previous
//
#include <hip/hip_runtime.h>
#include <math.h>

// ---------------------------------------------------------------------------
// bf16-MFMA pipeline v8:
//   gemm_qkv    : restructured for TLP — 256 thr, BM=64, N-half split (192),
//                 grid 512 -> 4 blocks/CU (40 KB LDS); same-M pair on same
//                 XCD (X re-read is L2 hit); launch_bounds(256,4) lifts the
//                 64-VGPR spill cap; corrected vmcnt counts (10/5/0)
//   flash_attn3 : + launch_bounds(512,4) (VGPR cap 128, was 64 -> spills)
//   gemm_out    : + launch_bounds(256,4)
//   others unchanged
// Layout: addr(tile,c,r,j) = ((tile*NC + c)*64 + r)*8 + j  (NC = K/8)
// ---------------------------------------------------------------------------

typedef __attribute__((ext_vector_type(8))) short bf16x8;
typedef __attribute__((ext_vector_type(4))) short bf16x4;
typedef __attribute__((ext_vector_type(4))) float f32x4;

#define FA_SCL2 0.12751886525137387f   // 128^-0.5 * log2(e)

__device__ __forceinline__ unsigned short f2bf(float f) {
    __bf16 h = (__bf16)f;                       // native cvt (RNE)
    return __builtin_bit_cast(unsigned short, h);
}
__device__ __forceinline__ float bf2f(unsigned short h) {
    union { unsigned u; float f; } v; v.u = ((unsigned)h) << 16;
    return v.f;
}
__device__ __forceinline__ f32x4 mfma16(bf16x8 a, bf16x8 b, f32x4 c) {
    return __builtin_amdgcn_mfma_f32_16x16x32_bf16(a, b, c, 0, 0, 0);
}
__device__ __forceinline__ void gl2lds16(const void* g, void* l) {
    __builtin_amdgcn_global_load_lds(
        (const __attribute__((address_space(1))) unsigned int*)g,
        (__attribute__((address_space(3))) unsigned int*)l, 16, 0, 0);
}
__device__ __forceinline__ f32x4 vmax4(f32x4 a, f32x4 b) {
    return f32x4{fmaxf(a[0], b[0]), fmaxf(a[1], b[1]),
                 fmaxf(a[2], b[2]), fmaxf(a[3], b[3])};
}

// ---------------------------------------------------------------------------
// W fp32 [384][1024] -> frag-major bf16. grid 192 x 256 thr.
// ---------------------------------------------------------------------------
__global__ __launch_bounds__(256)
void wcast(const float* __restrict__ W, unsigned short* __restrict__ wfm)
{
    const int idx = blockIdx.x * 256 + threadIdx.x;   // 49152 granules
    const int kc = idx & 127, r = idx >> 7;
    const float* g = W + (size_t)r * 1024 + kc * 8;
    float4 w0 = *(const float4*)g, w1 = *(const float4*)(g + 4);
    bf16x8 p;
    p[0] = (short)f2bf(w0.x); p[1] = (short)f2bf(w0.y);
    p[2] = (short)f2bf(w0.z); p[3] = (short)f2bf(w0.w);
    p[4] = (short)f2bf(w1.x); p[5] = (short)f2bf(w1.y);
    p[6] = (short)f2bf(w1.z); p[7] = (short)f2bf(w1.w);
    *(bf16x8*)&wfm[(size_t)(kc * 384 + r) * 8] = p;
}

// ---------------------------------------------------------------------------
// w_out fp32 [1024][128] -> frag-major bf16 64-row tiles. grid 64 x 256 thr.
// ---------------------------------------------------------------------------
__global__ __launch_bounds__(256)
void woutcast(const float* __restrict__ W, unsigned short* __restrict__ wofm)
{
    const int idx = blockIdx.x * 256 + threadIdx.x;   // 16384 granules
    const int c = idx & 15, rg = idx >> 4;            // rg in [0,1024)
    const float* g = W + (size_t)rg * 128 + c * 8;
    float4 w0 = *(const float4*)g, w1 = *(const float4*)(g + 4);
    bf16x8 p;
    p[0] = (short)f2bf(w0.x); p[1] = (short)f2bf(w0.y);
    p[2] = (short)f2bf(w0.z); p[3] = (short)f2bf(w0.w);
    p[4] = (short)f2bf(w1.x); p[5] = (short)f2bf(w1.y);
    p[6] = (short)f2bf(w1.z); p[7] = (short)f2bf(w1.w);
    *(bf16x8*)&wofm[((size_t)((rg >> 6) * 16 + c) * 64 + (rg & 63)) * 8] = p;
}

// ---------------------------------------------------------------------------
// Fused QKV projection v8. BM=64, BN=192 (N-half), BK=32. grid 512 x 256 thr.
// mt = bx&255 (M tile), nh = bx>>8 (N half) -> same-M pair shares XCD L2.
// 40 KB LDS -> 4 blocks/CU. A 2-deep reg prefetch; B triple-buffer gl2lds.
// ---------------------------------------------------------------------------
__global__ __launch_bounds__(256, 4)
void gemm_qkv(const float* __restrict__ X, const unsigned short* __restrict__ Wfm,
              unsigned short* __restrict__ qfm, unsigned short* __restrict__ kfm,
              unsigned short* __restrict__ vpl)
{
    __shared__ unsigned short Asl[2048];          // 4 KB (64 rows x 32 k)
    __shared__ unsigned short Bsl[3][6144];       // 3 x 12 KB (192 x 32)
    const int tid = threadIdx.x;
    const int wv = tid >> 6, lane = tid & 63;
    const int lm = lane & 15, quad = lane >> 4;
    const int mt = blockIdx.x & 255;
    const int nh = blockIdx.x >> 8;
    const int mb = mt * 64, nb = nh * 192;
    const int arow = tid >> 2, af4 = tid & 3;     // row, k-chunk (8 floats)

    f32x4 acc[4][3];
    #pragma unroll
    for (int i = 0; i < 4; ++i)
        #pragma unroll
        for (int j = 0; j < 3; ++j) acc[i][j] = f32x4{0.f, 0.f, 0.f, 0.f};

    const float* gx = X + (size_t)(mb + arow) * 1024 + af4 * 8;

    // B staging: 12 pieces of 1 KB; wave wv stages pieces wv*3 + {0,1,2}
    auto issueB = [&](int it, int buf) {
        #pragma unroll
        for (int i = 0; i < 3; ++i) {
            const int p = wv * 3 + i;
            const int kcl = p & 3, rg = p >> 2;
            gl2lds16(Wfm + ((size_t)((it * 4 + kcl) * 384) + nb + rg * 64) * 8 + lane * 8,
                     &Bsl[buf][(kcl * 192 + rg * 64) * 8]);
        }
    };

    // prologue: A(0), B(0), A(1), B(1) in flight (A-loads precede B per iter)
    float4 a00 = *(const float4*)gx;
    float4 a01 = *(const float4*)(gx + 4);
    issueB(0, 0);
    float4 a10 = *(const float4*)(gx + 32);
    float4 a11 = *(const float4*)(gx + 36);
    issueB(1, 1);

    auto step = [&](const int i, float4& fa, float4& fb) {
        __builtin_amdgcn_s_barrier();             // B1: Asl/Bsl[(i+2)%3] free
        {   // A(i) regs -> LDS (compiler auto-waits vmcnt for fa/fb)
            bf16x8 pk;
            pk[0] = (short)f2bf(fa.x); pk[1] = (short)f2bf(fa.y);
            pk[2] = (short)f2bf(fa.z); pk[3] = (short)f2bf(fa.w);
            pk[4] = (short)f2bf(fb.x); pk[5] = (short)f2bf(fb.y);
            pk[6] = (short)f2bf(fb.z); pk[7] = (short)f2bf(fb.w);
            *(bf16x8*)&Asl[(af4 * 64 + arow) * 8] = pk;
        }
        if (i < 30) {
            fa = *(const float4*)(gx + (i + 2) * 32);      // A(i+2), 2-iter slack
            fb = *(const float4*)(gx + (i + 2) * 32 + 4);
            issueB(i + 2, (i + 2) % 3);
            // outstanding: 8 (A(i+1),B(i+1),A(i+2)) + 5 just issued; B(i) done at <=10
            asm volatile("s_waitcnt vmcnt(10) lgkmcnt(0)" ::: "memory");
        } else if (i == 30) {
            asm volatile("s_waitcnt vmcnt(5) lgkmcnt(0)" ::: "memory");  // B(30) done
        } else {
            asm volatile("s_waitcnt vmcnt(0) lgkmcnt(0)" ::: "memory");
        }
        __builtin_amdgcn_s_barrier();             // B2: tile i ready
        const unsigned short* Bc = Bsl[i % 3];
        bf16x8 afr[4], bfr[3];
        #pragma unroll
        for (int i4 = 0; i4 < 4; ++i4)
            afr[i4] = *(const bf16x8*)&Asl[(quad * 64 + i4 * 16 + lm) * 8];
        #pragma unroll
        for (int j = 0; j < 3; ++j)
            bfr[j] = *(const bf16x8*)&Bc[(quad * 192 + wv * 48 + j * 16 + lm) * 8];
        #pragma unroll
        for (int i4 = 0; i4 < 4; ++i4)
            #pragma unroll
            for (int j = 0; j < 3; ++j)
                acc[i4][j] = mfma16(afr[i4], bfr[j], acc[i4][j]);
    };

    for (int p = 0; p < 16; ++p) { step(2 * p, a00, a01); step(2 * p + 1, a10, a11); }

    // epilogue: global col = nb + wv*48 + j*16 + lm; sect 0->Q(scaled),1->K,2->V
    #pragma unroll
    for (int j = 0; j < 3; ++j) {
        const int ncg = nb + wv * 48 + j * 16 + lm;   // frag never straddles 128
        const int sect = ncg >> 7, ncol = ncg & 127;
        if (sect == 2) {
            #pragma unroll
            for (int i = 0; i < 4; ++i)
                #pragma unroll
                for (int r = 0; r < 4; ++r)
                    vpl[(size_t)(mb + i * 16 + quad * 4 + r) * 128 + ncol]
                        = f2bf(acc[i][j][r]);
        } else {
            unsigned short* dst = sect ? kfm : qfm;
            const float scl = sect ? 1.f : FA_SCL2;
            const size_t cb = ((size_t)mt * 16 + (ncol >> 3)) * 512 + (ncol & 7);
            #pragma unroll
            for (int i = 0; i < 4; ++i)
                #pragma unroll
                for (int r = 0; r < 4; ++r)
                    dst[cb + (size_t)(i * 16 + quad * 4 + r) * 8]
                        = f2bf(acc[i][j][r] * scl);
        }
    }
}

// ---------------------------------------------------------------------------
// V plain -> Vfm. grid 256 x 256 thr. (unchanged)
// ---------------------------------------------------------------------------
__global__ __launch_bounds__(256)
void transpose_v(const unsigned short* __restrict__ V, unsigned short* __restrict__ Vfm)
{
    __shared__ unsigned short T[128 * 72];   // [d][key-rel], stride 72
    const int tid = threadIdx.x;
    const int b  = blockIdx.x >> 6;
    const int kt = blockIdx.x & 63;
    const unsigned short* src = V + ((size_t)b * 4096 + kt * 64) * 128;
    #pragma unroll
    for (int i = 0; i < 4; ++i) {
        const int idx = tid + i * 256;
        const int key = idx >> 4, c8 = (idx & 15) * 8;
        bf16x8 d = *(const bf16x8*)(src + key * 128 + c8);
        #pragma unroll
        for (int e = 0; e < 8; ++e) T[(c8 + e) * 72 + key] = (unsigned short)d[e];
    }
    __syncthreads();
    unsigned short* dst = Vfm + (size_t)(b * 64 + kt) * 8192;
    #pragma unroll
    for (int i = 0; i < 4; ++i) {
        const int o = tid + i * 256;
        const int d = o & 127, c = o >> 7;
        bf16x8 x = *(const bf16x8*)&T[d * 72 + c * 8];
        *(bf16x8*)(dst + ((size_t)c * 128 + d) * 8) = x;
    }
}

// ---------------------------------------------------------------------------
// Flash attention v8: as v7 + launch_bounds(512,4) (VGPR cap 128).
// ---------------------------------------------------------------------------
__global__ __launch_bounds__(512, 4)
void flash_attn3(const unsigned short* __restrict__ Qfm, const unsigned short* __restrict__ Kfm,
                 const unsigned short* __restrict__ Vfm,
                 unsigned short* __restrict__ Opart, float* __restrict__ Ml)
{
    __shared__ unsigned short Klds[2][8192];    // 2 x 16 KB (Q stages both)
    __shared__ unsigned short Vlds[2][8192];    // 2 x 16 KB
    __shared__ unsigned short Plds[8][1024];    // per-wave P (A-frag), 16 KB

    const int tid = threadIdx.x;
    const int wv = tid >> 6, lane = tid & 63;
    const int lm = lane & 15, quad = lane >> 4;

    // XCD-pinned, load-balanced decode (heavy blocks first)
    const int bx = blockIdx.x;
    const int xcd = bx & 7;
    const int b   = xcd >> 1;                    // batch on XCD pair {2b,2b+1}
    const int r   = (bx >> 3) * 2 + (xcd & 1);   // [0,128) per batch
    const int sp  = r & 3;
    const int Qi  = (r < 64) ? (16 + (r >> 2)) : (15 - ((r - 64) >> 2));
    const int n   = 2 * Qi + 2;                  // key tiles for this Q-block
    const int cnt = (n >> 2) + ((sp < (n & 3)) ? 1 : 0);
    const int ktb = sp * (n >> 2) + ((sp < (n & 3)) ? sp : (n & 3));
    const int kte = ktb + cnt;
    const int qtw = 2 * Qi + (wv >> 2);          // wave's 64-row q-tile
    const int rw  = (wv & 3) * 16;               // wave's rows inside the tile

    const int qt0 = 2 * Qi;
    const size_t ob0 = (size_t)((b * 64 + qt0) * 4 + sp) * 8192;
    const size_t ob1 = ob0 + 4 * 8192;
    const int mlb0 = ((b * 64 + qt0) * 4 + sp) * 128, mlb1 = mlb0 + 512;

    if (cnt == 0) {                      // neutral partial (both tiles)
        bf16x8 z = {0, 0, 0, 0, 0, 0, 0, 0};
        #pragma unroll
        for (int t = 0; t < 2; ++t) {
            *(bf16x8*)&Opart[ob0 + (size_t)(tid + t * 512) * 8] = z;
            *(bf16x8*)&Opart[ob1 + (size_t)(tid + t * 512) * 8] = z;
        }
        if (tid < 64) { Ml[mlb0 + tid] = -INFINITY; Ml[mlb1 + tid] = -INFINITY; }
        else if (tid < 128) { Ml[mlb0 + tid] = 0.f; Ml[mlb1 + tid] = 0.f; }
        return;
    }

    // stage both Q tiles (32 KB), pull frags to regs
    {
        const size_t qb = (size_t)(b * 64 + qt0) * 8192;
        #pragma unroll
        for (int i = 0; i < 4; ++i) {
            const int p = wv * 4 + i;
            gl2lds16(Qfm + qb + (size_t)p * 512 + lane * 8, &Klds[0][0] + p * 512);
        }
    }
    __syncthreads();
    bf16x8 qf[4];
    {
        const unsigned short* Qt = &Klds[wv >> 2][0];
        #pragma unroll
        for (int c = 0; c < 4; ++c)
            qf[c] = *(const bf16x8*)&Qt[((c * 4 + quad) * 64 + rw + lm) * 8];
    }
    asm volatile("s_waitcnt lgkmcnt(0)" ::: "memory");   // qf secured
    __builtin_amdgcn_s_barrier();

    // prologue: first K/V tile -> buf 0 (overwrites Q: safe)
    {
        const size_t kb = (size_t)(b * 64 + ktb) * 8192;
        #pragma unroll
        for (int i = 0; i < 2; ++i) {
            const int pc = wv * 2 + i;
            gl2lds16(Kfm + kb + pc * 512 + lane * 8, &Klds[0][pc * 512]);
            gl2lds16(Vfm + kb + pc * 512 + lane * 8, &Vlds[0][pc * 512]);
        }
    }

    f32x4 oacc[8];
    #pragma unroll
    for (int oc = 0; oc < 8; ++oc) oacc[oc] = f32x4{0.f, 0.f, 0.f, 0.f};
    f32x4 m4 = f32x4{-INFINITY, -INFINITY, -INFINITY, -INFINITY};
    f32x4 lacc = f32x4{0.f, 0.f, 0.f, 0.f};
    unsigned short* Pw = Plds[wv];
    const short ONE = (short)0x3F80;             // bf16 1.0
    const bf16x8 ONESB = {ONE, ONE, ONE, ONE, ONE, ONE, ONE, ONE};

    for (int kt = ktb; kt < kte; ++kt) {
        const int cu = (kt - ktb) & 1;
        __builtin_amdgcn_s_barrier();    // B1: buf[cu^1] free to overwrite
        if (kt + 1 < kte) {
            const size_t kb = (size_t)(b * 64 + kt + 1) * 8192;
            #pragma unroll
            for (int i = 0; i < 2; ++i) {
                const int pc = wv * 2 + i;
                gl2lds16(Kfm + kb + pc * 512 + lane * 8, &Klds[cu ^ 1][pc * 512]);
                gl2lds16(Vfm + kb + pc * 512 + lane * 8, &Vlds[cu ^ 1][pc * 512]);
            }
            asm volatile("s_waitcnt vmcnt(4)" ::: "memory");  // tile kt done
        } else {
            asm volatile("s_waitcnt vmcnt(0)" ::: "memory");
        }
        __builtin_amdgcn_s_barrier();    // B2: buf[cu] ready
        if (kt > qtw) continue;          // wave's rows fully masked this tile

        const unsigned short* Kc = &Klds[cu][0];
        const unsigned short* Vc = &Vlds[cu][0];

        // S = Q K^T (Q pre-scaled to base-2)
        f32x4 sv[4];
        __builtin_amdgcn_s_setprio(1);
        #pragma unroll
        for (int ct = 0; ct < 4; ++ct) {
            f32x4 a = f32x4{0.f, 0.f, 0.f, 0.f};
            #pragma unroll
            for (int c = 0; c < 4; ++c) {
                bf16x8 kf = *(const bf16x8*)&Kc[((c * 4 + quad) * 64 + ct * 16 + lm) * 8];
                a = mfma16(qf[c], kf, a);
            }
            sv[ct] = a;
        }
        __builtin_amdgcn_s_setprio(0);
        if (kt == qtw) {                 // diagonal tile: mask key > row
            #pragma unroll
            for (int ct = 0; ct < 4; ++ct) {
                const int dg = ct * 16 + lm - rw - quad * 4;
                #pragma unroll
                for (int rr = 0; rr < 4; ++rr)
                    if (dg > rr) sv[ct][rr] = -INFINITY;
            }
        }
        // defer-max online softmax (base 2)
        const f32x4 pmax = vmax4(vmax4(sv[0], sv[1]), vmax4(sv[2], sv[3]));
        const float dm = fmaxf(fmaxf(pmax[0] - m4[0], pmax[1] - m4[1]),
                               fmaxf(pmax[2] - m4[2], pmax[3] - m4[3]));
        if (!__all(dm <= 8.f)) {
            f32x4 rmax = pmax;
            #pragma unroll
            for (int d = 1; d < 16; d <<= 1) {
                f32x4 o;
                #pragma unroll
                for (int e = 0; e < 4; ++e) o[e] = __shfl_xor(rmax[e], d);
                rmax = vmax4(rmax, o);
            }
            const f32x4 mnew = vmax4(m4, rmax);       // finite here (diag row)
            f32x4 alpha;
            #pragma unroll
            for (int e = 0; e < 4; ++e) alpha[e] = __builtin_amdgcn_exp2f(m4[e] - mnew[e]);
            m4 = mnew;
            #pragma unroll
            for (int oc = 0; oc < 8; ++oc) oacc[oc] *= alpha;
            lacc *= alpha;
        }
        #pragma unroll
        for (int ct = 0; ct < 4; ++ct)
            #pragma unroll
            for (int rr = 0; rr < 4; ++rr)
                sv[ct][rr] = __builtin_amdgcn_exp2f(sv[ct][rr] - m4[rr]);
        // P -> wave-private LDS (A-frag layout)
        #pragma unroll
        for (int ct = 0; ct < 4; ++ct) {
            const int cb = ((ct * 2 + (lm >> 3)) * 16 + quad * 4) * 8 + (lm & 7);
            #pragma unroll
            for (int rr = 0; rr < 4; ++rr)
                Pw[cb + rr * 8] = f2bf(sv[ct][rr]);
        }
        // O += P V ; l += P 1  (row-sum via ones-column MFMA)
        __builtin_amdgcn_s_setprio(1);
        #pragma unroll
        for (int s = 0; s < 2; ++s) {
            bf16x8 pf = *(const bf16x8*)&Pw[((s * 4 + quad) * 16 + lm) * 8];
            lacc = mfma16(pf, ONESB, lacc);
            #pragma unroll
            for (int oc = 0; oc < 8; ++oc) {
                bf16x8 vf = *(const bf16x8*)&Vc[((s * 4 + quad) * 128 + oc * 16 + lm) * 8];
                oacc[oc] = mfma16(pf, vf, oacc[oc]);
            }
        }
        __builtin_amdgcn_s_setprio(0);
    }

    // epilogue: per-wave 64-row tile qtw, rows rw..rw+15
    const size_t obw = (size_t)((b * 64 + qtw) * 4 + sp) * 8192;
    const int mlw = ((b * 64 + qtw) * 4 + sp) * 128;
    #pragma unroll
    for (int oc = 0; oc < 8; ++oc) {
        const size_t cb = obw + (size_t)((oc * 2 + (lm >> 3)) * 64
                          + rw + quad * 4) * 8 + (lm & 7);
        #pragma unroll
        for (int rr = 0; rr < 4; ++rr)
            Opart[cb + rr * 8] = f2bf(oacc[oc][rr]);
    }
    if (lm == 0)
        #pragma unroll
        for (int rr = 0; rr < 4; ++rr) {
            const int row = rw + quad * 4 + rr;
            Ml[mlw + row] = m4[rr];
            Ml[mlw + 64 + row] = lacc[rr];
        }
}

// ---------------------------------------------------------------------------
// Merge 4 splits -> Ofm. grid 256 x 256 thr. (unchanged; base-2 m/l)
// ---------------------------------------------------------------------------
__global__ __launch_bounds__(256)
void fa_combine(const unsigned short* __restrict__ Opart, const float* __restrict__ Ml,
                unsigned short* __restrict__ Ofm)
{
    const int bq = blockIdx.x;
    const int tid = threadIdx.x;
    const size_t pbase = (size_t)bq * 4 * 8192;
    const int mlb = bq * 4 * 128;
    #pragma unroll
    for (int t = 0; t < 4; ++t) {
        const int g = tid + t * 256;
        const int r = g & 63;
        float m[4], l[4];
        #pragma unroll
        for (int s = 0; s < 4; ++s) {
            m[s] = Ml[mlb + s * 128 + r];
            l[s] = Ml[mlb + s * 128 + 64 + r];
        }
        const float M = fmaxf(fmaxf(m[0], m[1]), fmaxf(m[2], m[3]));
        float a[4], den = 0.f;
        #pragma unroll
        for (int s = 0; s < 4; ++s) {
            a[s] = __builtin_amdgcn_exp2f(m[s] - M);
            den += a[s] * l[s];
        }
        const float rsc = 1.f / den;
        float acc[8] = {};
        #pragma unroll
        for (int s = 0; s < 4; ++s) {
            bf16x8 x = *(const bf16x8*)&Opart[pbase + (size_t)s * 8192 + (size_t)g * 8];
            #pragma unroll
            for (int e = 0; e < 8; ++e) acc[e] += a[s] * bf2f((unsigned short)x[e]);
        }
        bf16x8 o;
        #pragma unroll
        for (int e = 0; e < 8; ++e) o[e] = f2bf(acc[e] * rsc);
        *(bf16x8*)&Ofm[(size_t)bq * 8192 + (size_t)g * 8] = o;
    }
}

// ---------------------------------------------------------------------------
// Output projection + bias. grid(128,8) x 256 thr. + launch_bounds(256,4).
// ---------------------------------------------------------------------------
__global__ __launch_bounds__(256, 4)
void gemm_out(const unsigned short* __restrict__ Ain, const unsigned short* __restrict__ Wofm,
              const float* __restrict__ bias, float* __restrict__ out)
{
    __shared__ unsigned short Bsl[16384];      // 32 KB
    __shared__ unsigned short Asl[2][4096];    // 2 x 8 KB
    const int tid = threadIdx.x;
    const int mb = blockIdx.x * 128;
    const int nb = blockIdx.y * 128;
    const int wv = tid >> 6, lane = tid & 63;
    const int wr = (wv >> 1) * 64, wc = (wv & 1) * 64;
    const int lm = lane & 15, quad = lane >> 4;

    #pragma unroll
    for (int i = 0; i < 8; ++i) {
        const int p = wv * 8 + i;
        gl2lds16(Wofm + (size_t)(((nb >> 6) + (p >> 4)) * 16 + (p & 15)) * 512 + lane * 8,
                 &Bsl[p * 512]);
    }
    #pragma unroll
    for (int i = 0; i < 2; ++i) {
        const int id = wv * 2 + i, t = id >> 2, kcl = id & 3;
        gl2lds16(Ain + (size_t)((mb >> 6) + t) * 8192 + kcl * 512 + lane * 8,
                 &Asl[0][(t * 4 + kcl) * 512]);
    }

    f32x4 acc[4][4];
    #pragma unroll
    for (int i = 0; i < 4; ++i)
        #pragma unroll
        for (int j = 0; j < 4; ++j) acc[i][j] = f32x4{0.f, 0.f, 0.f, 0.f};

    for (int kt = 0; kt < 4; ++kt) {
        __builtin_amdgcn_s_barrier();
        if (kt < 3) {
            #pragma unroll
            for (int i = 0; i < 2; ++i) {
                const int id = wv * 2 + i, t = id >> 2, kcl = id & 3;
                gl2lds16(Ain + (size_t)((mb >> 6) + t) * 8192 + ((kt + 1) * 4 + kcl) * 512 + lane * 8,
                         &Asl[(kt + 1) & 1][(t * 4 + kcl) * 512]);
            }
            asm volatile("s_waitcnt vmcnt(2)" ::: "memory");
        } else {
            asm volatile("s_waitcnt vmcnt(0)" ::: "memory");
        }
        __builtin_amdgcn_s_barrier();
        const unsigned short* Ac = Asl[kt & 1];
        bf16x8 af[4], bfr[4];
        #pragma unroll
        for (int i = 0; i < 4; ++i)
            af[i] = *(const bf16x8*)&Ac[(((wv >> 1) * 4 + quad) * 64 + i * 16 + lm) * 8];
        #pragma unroll
        for (int j = 0; j < 4; ++j)
            bfr[j] = *(const bf16x8*)&Bsl[(((wc >> 6) * 16 + kt * 4 + quad) * 64 + j * 16 + lm) * 8];
        #pragma unroll
        for (int i = 0; i < 4; ++i)
            #pragma unroll
            for (int j = 0; j < 4; ++j)
                acc[i][j] = mfma16(af[i], bfr[j], acc[i][j]);
    }

    #pragma unroll
    for (int j = 0; j < 4; ++j) {
        const int col = nb + wc + j * 16 + lm;
        const float bv = bias[col];
        #pragma unroll
        for (int i = 0; i < 4; ++i)
            #pragma unroll
            for (int r = 0; r < 4; ++r) {
                const int m = mb + wr + i * 16 + quad * 4 + r;
                out[(size_t)m * 1024 + col] = acc[i][j][r] + bv;
            }
    }
}

// ---------------------------------------------------------------------------
extern "C" void kernel_launch(void* const* d_in, const int* in_sizes, int n_in,
                              void* d_out, int out_size, void* d_ws, size_t ws_size,
                              hipStream_t stream)
{
    (void)in_sizes; (void)n_in; (void)out_size; (void)ws_size;
    const float* x     = (const float*)d_in[0];
    const float* w_qkv = (const float*)d_in[1];
    const float* w_out = (const float*)d_in[2];
    const float* b_out = (const float*)d_in[3];
    float* out = (float*)d_out;
    unsigned short* ws = (unsigned short*)d_ws;

    const size_t NE = (size_t)16384 * 128;          // 2 097 152
    unsigned short* qfm = ws;                        // 4 MB (Ofm aliases after flash)
    unsigned short* kfm = ws + NE;                   // 4 MB
    unsigned short* vpl = ws + 2 * NE;               // 4 MB
    unsigned short* vfm = ws + 3 * NE;               // 4 MB
    unsigned short* op  = ws + 4 * NE;               // Opart 16.8 MB
    float*          ml  = (float*)(ws + 8 * NE);     // 0.5 MB
    unsigned short* ofm = qfm;                       // alias: Qfm dead after flash
    unsigned short* wfm = op;                        // alias: dead before flash
    unsigned short* wofm = vpl;                      // alias: vpl dead after transpose_v

    hipLaunchKernelGGL(wcast,       dim3(192),    dim3(256), 0, stream, w_qkv, wfm);
    hipLaunchKernelGGL(gemm_qkv,    dim3(512),    dim3(256), 0, stream, x, wfm, qfm, kfm, vpl);
    hipLaunchKernelGGL(transpose_v, dim3(256),    dim3(256), 0, stream, vpl, vfm);
    hipLaunchKernelGGL(woutcast,    dim3(64),     dim3(256), 0, stream, w_out, wofm);
    hipLaunchKernelGGL(flash_attn3, dim3(512),    dim3(512), 0, stream, qfm, kfm, vfm, op, ml);
    hipLaunchKernelGGL(fa_combine,  dim3(256),    dim3(256), 0, stream, op, ml, ofm);
    hipLaunchKernelGGL(gemm_out,    dim3(128, 8), dim3(256), 0, stream, ofm, wofm, b_out, out);
}